// Round 6
// baseline (17089.728 us; speedup 1.0000x reference)
//
#include <hip/hip_runtime.h>
#include <math.h>

typedef unsigned short u16;
typedef __attribute__((ext_vector_type(8))) short short8;
typedef __attribute__((ext_vector_type(4))) float float4v;

#define HH   512
#define BB   256
#define TLEN 512
#define DD   64

__device__ __forceinline__ float sigm(float x) { return 1.0f / (1.0f + __expf(-x)); }

__device__ __forceinline__ u16 bf16rn(float v) {
    unsigned u = __float_as_uint(v);
    u += 0x7fffu + ((u >> 16) & 1u);
    return (u16)(u >> 16);
}
__device__ __forceinline__ float bf16tf(u16 h) { return __uint_as_float(((unsigned)h) << 16); }

// ---------------- precompute kernels ----------------

__global__ __launch_bounds__(256) void split_kernel(const float* __restrict__ src,
                                                    u16* __restrict__ hi, u16* __restrict__ lo, int n)
{
    for (int i = blockIdx.x * 256 + threadIdx.x; i < n; i += gridDim.x * 256) {
        float v = src[i];
        u16 h = bf16rn(v);
        hi[i] = h;
        lo[i] = bf16rn(v - bf16tf(h));
    }
}

__global__ __launch_bounds__(256) void zero_kernel(unsigned* p, int n)
{
    int i = blockIdx.x * 256 + threadIdx.x;
    if (i < n) p[i] = 0u;
}

// ---------------- persistent fused LSTM ----------------
// Round-6 = round-5 structure with the register budget FIXED.
// Round-5 regression root-cause (counter-proven): __launch_bounds__(512,2)
// granted only a 128-VGPR arch budget (2-blocks/CU sizing) while demand was
// ~230 -> ~30 regs/thread spilled to scratch = 16.4 MB/step HBM writeback
// (WRITE_SIZE 5.3e5 -> 8.9e6 KB). Grid is 256 blocks on 256 CUs, so a 2nd
// block/CU never exists: (512,1) doubles the budget at zero occupancy cost.
//  * Wave = (gate-pair gp, k-quarter q): 2x LDS A-read amplification (vs 4x).
//  * A staged via global_load_lds (linear LDS dest, inverse-swizzled per-lane
//    global source; swizzled ds_read_b128) -> no ds_write in the LDS pipe.
//  * k-quarter partials reduced via 3-stage LDS tree; epilogue = round-4 math.
//  * Inter-block sync: lockstep gen-protocol (rounds 2/4/5 proven), tree
//    arrival (8 sub-counters -> top -> gen flip).
// LDS map (64 KB): staging 2 bufs x 32KB (4 slots x [hi 4KB | lo 4KB]).
// Exchange aliases it after the chunk loop: R1 0..32KB, R2 32..48KB, G 48..64KB.

template<int NCH, int C1, bool ROLE1>
__device__ void lstm_body(
    const u16* __restrict__ X1h, const u16* __restrict__ X1l,
    const u16* __restrict__ B1h, const u16* __restrict__ B1l, const int ldb1,
    const u16* __restrict__ B2h, const u16* __restrict__ B2l,
    const float* __restrict__ pbi, const float* __restrict__ pbh,
    u16* __restrict__ h0hA, u16* __restrict__ h0lA,
    u16* __restrict__ h0hB, u16* __restrict__ h0lB,
    u16* __restrict__ h1hA, u16* __restrict__ h1lA,
    u16* __restrict__ h1hB, u16* __restrict__ h1lB,
    float* __restrict__ h1last,
    unsigned* bar_g, const int aid,
    const int m0, const int j0, u16* smem)
{
    const int tid  = threadIdx.x;
    const int lane = tid & 63;
    const int wv   = tid >> 6;
    const int q    = wv & 3;      // k-quarter
    const int gp   = wv >> 2;     // gate pair (0: i,f  1: g,o)

    constexpr int QB = NCH / 4, QR = NCH % 4;
    constexpr int NKTMAX = (NCH + 3) / 4;
    const int cntq = QB + (q < QR ? 1 : 0);
    const int stq  = q * QB + (q < QR ? q : QR);

    char* smemB = (char*)smem;

    // ---- B slice -> registers, once: gates {2gp, 2gp+1}, chunks [stq, stq+cntq) ----
    short8 rBh[2][NKTMAX], rBl[2][NKTMAX];
    {
        const int kq8 = (lane >> 4) * 8;
#pragma unroll
        for (int gg = 0; gg < 2; ++gg) {
            const size_t brow = (size_t)((gp * 2 + gg) * HH + j0 + (lane & 15));
#pragma unroll
            for (int i = 0; i < NKTMAX; ++i) {
                if (i < cntq) {
                    const int kt = stq + i;
                    const u16 *ph, *pl;
                    if (kt < C1) {
                        ph = B1h + brow * (size_t)ldb1 + kt * 32 + kq8;
                        pl = B1l + brow * (size_t)ldb1 + kt * 32 + kq8;
                    } else {
                        ph = B2h + brow * HH + (size_t)(kt - C1) * 32 + kq8;
                        pl = B2l + brow * HH + (size_t)(kt - C1) * 32 + kq8;
                    }
                    rBh[gg][i] = *(const short8*)ph;
                    rBl[gg][i] = *(const short8*)pl;
                }
            }
        }
    }

    // ---- staging constants (global_load_lds) ----
    // wave (gp,q) stages slot q, part hl=gp. Instr j fills rows [j*16, j*16+16).
    // LDS(row, s) holds data slot q4 = s ^ ((row>>1)&3) (XOR involution).
    const int r0     = lane >> 2;                                 // row within 16
    const int ksubst = (((lane & 3) ^ ((lane >> 3) & 3)) * 8);    // inv-swizzled k sub (elems)
    // ---- A-frag read constants (swizzled) ----
    const int abyte  = (lane & 15) * 64 + (((lane >> 4) ^ (((lane & 15) >> 1) & 3)) * 16);

    // ---- epilogue constants (round-4 verbatim mapping) ----
    const int jj  = j0 + (tid & 15);
    const int jl  = tid & 15;
    const int mb2 = (tid >> 4) * 2;
    const float bI = pbi[jj] + pbh[jj];
    const float bF = pbi[HH + jj] + pbh[HH + jj];
    const float bG = pbi[2 * HH + jj] + pbh[2 * HH + jj];
    const float bO = pbi[3 * HH + jj] + pbh[3 * HH + jj];
    float cst0 = 0.f, cst1 = 0.f;   // c-state in registers

    unsigned* subp = bar_g + (aid >> 3) * 16;   // 8 sub-counters, 64B apart
    unsigned* topp = bar_g + 128;
    unsigned* genp = bar_g + 144;

    for (int n = 0; n <= TLEN; ++n) {
        const int rb = n & 1;
        const bool active = ROLE1 ? (n > 0) : (n < TLEN);
        if (active) {
            const u16 *A1h_, *A1l_, *A2h_, *A2l_;
            u16 *wh, *wl;
            size_t ld1;
            if (ROLE1) {
                A1h_ = rb ? h0hB : h0hA; A1l_ = rb ? h0lB : h0lA;
                A2h_ = rb ? h1hB : h1hA; A2l_ = rb ? h1lB : h1lA;
                wh   = rb ? h1hA : h1hB; wl   = rb ? h1lA : h1lB;
                ld1 = HH;
            } else {
                A1h_ = X1h + (size_t)n * DD; A1l_ = X1l + (size_t)n * DD;
                A2h_ = rb ? h0hB : h0hA;     A2l_ = rb ? h0lB : h0lA;
                wh   = rb ? h0hA : h0hB;     wl   = rb ? h0lA : h0lB;
                ld1 = (size_t)TLEN * DD;
            }

            auto stage = [&](int kt, int bufoff) {
                const u16* base; size_t ld; int ko;
                if (kt < C1) { base = gp ? A1l_ : A1h_; ld = ld1; ko = kt * 32; }
                else         { base = gp ? A2l_ : A2h_; ld = HH;  ko = (kt - C1) * 32; }
                const u16* src = base + (size_t)(m0 + r0) * ld + ko + ksubst;
                char* ldsb = smemB + bufoff + q * 8192 + gp * 4096;
#pragma unroll
                for (int j = 0; j < 4; ++j) {
                    __builtin_amdgcn_global_load_lds(
                        (const __attribute__((address_space(1))) unsigned int*)(src + (size_t)j * 16 * ld),
                        (__attribute__((address_space(3))) unsigned int*)(ldsb + j * 1024),
                        16, 0, 0);
                }
            };

            float4v acc[2][4];
#pragma unroll
            for (int gg = 0; gg < 2; ++gg)
#pragma unroll
                for (int mt = 0; mt < 4; ++mt) acc[gg][mt] = (float4v){0.f, 0.f, 0.f, 0.f};

            stage(stq, 0);
            __syncthreads();           // buf0 DMA drained (vmcnt in barrier)

#pragma unroll
            for (int i = 0; i < NKTMAX; ++i) {
                if (i + 1 < cntq) stage(stq + i + 1, ((i + 1) & 1) * 32768);
                if (i < cntq) {
                    const int bb = (i & 1) * 32768 + q * 8192;
                    short8 aH[4], aL[4];
#pragma unroll
                    for (int mt = 0; mt < 4; ++mt) {
                        aH[mt] = *(const short8*)(smemB + bb + mt * 1024 + abyte);
                        aL[mt] = *(const short8*)(smemB + bb + 4096 + mt * 1024 + abyte);
                    }
#pragma unroll
                    for (int gg = 0; gg < 2; ++gg)
#pragma unroll
                        for (int mt = 0; mt < 4; ++mt) {
                            acc[gg][mt] = __builtin_amdgcn_mfma_f32_16x16x32_bf16(aH[mt], rBh[gg][i], acc[gg][mt], 0, 0, 0);
                            acc[gg][mt] = __builtin_amdgcn_mfma_f32_16x16x32_bf16(aH[mt], rBl[gg][i], acc[gg][mt], 0, 0, 0);
                            acc[gg][mt] = __builtin_amdgcn_mfma_f32_16x16x32_bf16(aL[mt], rBh[gg][i], acc[gg][mt], 0, 0, 0);
                        }
                }
                __syncthreads();       // my DMA drained; everyone's reads done
            }

            // ---- k-quarter reduction tree (LDS aliases staging; loop done) ----
            // R1: q in {1,3} write [idx8][lane] blocks; pair p=q>>1.
            if (q & 1) {
                char* p = smemB + (((gp << 1) | (q >> 1)) * 8192) + lane * 16;
#pragma unroll
                for (int gg = 0; gg < 2; ++gg)
#pragma unroll
                    for (int mt = 0; mt < 4; ++mt)
                        *(float4v*)(p + (gg * 4 + mt) * 1024) = acc[gg][mt];
            }
            __syncthreads();
            if (!(q & 1)) {
                char* p = smemB + (((gp << 1) | (q >> 1)) * 8192) + lane * 16;
#pragma unroll
                for (int gg = 0; gg < 2; ++gg)
#pragma unroll
                    for (int mt = 0; mt < 4; ++mt)
                        acc[gg][mt] += *(const float4v*)(p + (gg * 4 + mt) * 1024);
                if (q == 2) {   // R2 write
                    char* p2 = smemB + 32768 + gp * 8192 + lane * 16;
#pragma unroll
                    for (int gg = 0; gg < 2; ++gg)
#pragma unroll
                        for (int mt = 0; mt < 4; ++mt)
                            *(float4v*)(p2 + (gg * 4 + mt) * 1024) = acc[gg][mt];
                }
            }
            __syncthreads();
            if (q == 0) {       // R2 read + final gather into G[4g][16j][16 s-slots]
                char* p2 = smemB + 32768 + gp * 8192 + lane * 16;
#pragma unroll
                for (int gg = 0; gg < 2; ++gg)
#pragma unroll
                    for (int mt = 0; mt < 4; ++mt)
                        acc[gg][mt] += *(const float4v*)(p2 + (gg * 4 + mt) * 1024);
                const int jw = lane & 15, qw = lane >> 4;
#pragma unroll
                for (int gg = 0; gg < 2; ++gg)
#pragma unroll
                    for (int mt = 0; mt < 4; ++mt) {
                        const int g = gp * 2 + gg;
                        const int s = mt * 4 + qw;      // 4-row group index
                        *(float4v*)(smemB + 49152 +
                            (((g * 16 + jw) * 16) + (s ^ (jw & 7))) * 16) = acc[gg][mt];
                    }
            }
            __syncthreads();

            // ---- epilogue: all 512 threads, round-4 math/mapping ----
#pragma unroll
            for (int p = 0; p < 2; ++p) {
                const int m = mb2 + p;
                float gv[4];
#pragma unroll
                for (int g = 0; g < 4; ++g)
                    gv[g] = *(const float*)(smemB + 49152 +
                        (((g * 16 + jl) * 16) + ((m >> 2) ^ (jl & 7))) * 16 + (m & 3) * 4);
                const float gi = gv[0] + bI;
                const float gf = gv[1] + bF;
                const float gG = gv[2] + bG;
                const float go = gv[3] + bO;
                const float cp = p ? cst1 : cst0;
                const float cn = sigm(gf) * cp + sigm(gi) * tanhf(gG);
                const float h  = sigm(go) * tanhf(cn);
                if (p) cst1 = cn; else cst0 = cn;
                const size_t off = (size_t)(m0 + m) * HH + jj;
                const u16 hv = bf16rn(h);
                wh[off] = hv;
                wl[off] = bf16rn(h - bf16tf(hv));
                if (ROLE1 && n == TLEN) h1last[off] = h;
            }
        }

        // ---- inter-block barrier: rounds-2/4 gen protocol, tree arrival ----
        __syncthreads();   // drains vmcnt(0): h stores in L2 before release
        if (tid == 0) {
            const unsigned g0 = __hip_atomic_load(genp, __ATOMIC_RELAXED, __HIP_MEMORY_SCOPE_AGENT);
            const unsigned a = __hip_atomic_fetch_add(subp, 1u, __ATOMIC_ACQ_REL, __HIP_MEMORY_SCOPE_AGENT);
            if (a == 7u) {
                __hip_atomic_store(subp, 0u, __ATOMIC_RELAXED, __HIP_MEMORY_SCOPE_AGENT);
                const unsigned t = __hip_atomic_fetch_add(topp, 1u, __ATOMIC_ACQ_REL, __HIP_MEMORY_SCOPE_AGENT);
                if (t == 7u) {
                    __hip_atomic_store(topp, 0u, __ATOMIC_RELAXED, __HIP_MEMORY_SCOPE_AGENT);
                    __hip_atomic_store(genp, g0 + 1u, __ATOMIC_RELEASE, __HIP_MEMORY_SCOPE_AGENT);
                }
            }
            int sp = 0;
            while (__hip_atomic_load(genp, __ATOMIC_RELAXED, __HIP_MEMORY_SCOPE_AGENT) == g0) {
                __builtin_amdgcn_s_sleep(1);
                if ((++sp & 63) == 0)   // safety net: periodic coherent-forcing poll
                    (void)__hip_atomic_load(genp, __ATOMIC_ACQUIRE, __HIP_MEMORY_SCOPE_AGENT);
            }
            // single acquire: L1/L2 fresh for next step's h reads (B is in regs)
            (void)__hip_atomic_load(genp, __ATOMIC_ACQUIRE, __HIP_MEMORY_SCOPE_AGENT);
        }
        __syncthreads();
    }
}

__global__ __launch_bounds__(512, 1) void lstm_persistent(
    const u16* __restrict__ xhi, const u16* __restrict__ xlo,
    const u16* __restrict__ Wih0h, const u16* __restrict__ Wih0l,
    const u16* __restrict__ Whh0h, const u16* __restrict__ Whh0l,
    const u16* __restrict__ Wih1h, const u16* __restrict__ Wih1l,
    const u16* __restrict__ Whh1h, const u16* __restrict__ Whh1l,
    const float* __restrict__ bi0, const float* __restrict__ bh0,
    const float* __restrict__ bi1, const float* __restrict__ bh1,
    u16* h0hA, u16* h0lA, u16* h0hB, u16* h0lB,
    u16* h1hA, u16* h1lA, u16* h1hB, u16* h1lB,
    float* __restrict__ h1last, unsigned* bar)
{
    __shared__ u16 smem[32768];   // 64 KB: staging 2x32KB / exchange aliased
    const bool role1 = (blockIdx.x >= 128);
    const int idx = blockIdx.x & 127;
    const int m0 = (idx & 3) * 64;
    const int j0 = (idx >> 2) * 16;
    const int gid = idx & 3;
    unsigned* bar_g = bar + gid * 256;              // 1 KB per m-group
    const int aid = (role1 ? 32 : 0) + (idx >> 2);  // arrival id 0..63

    if (role1)
        lstm_body<32, 16, true>(nullptr, nullptr,
            Wih1h, Wih1l, HH, Whh1h, Whh1l, bi1, bh1,
            h0hA, h0lA, h0hB, h0lB, h1hA, h1lA, h1hB, h1lB,
            h1last, bar_g, aid, m0, j0, smem);
    else
        lstm_body<18, 2, false>(xhi, xlo,
            Wih0h, Wih0l, DD, Whh0h, Whh0l, bi0, bh0,
            h0hA, h0lA, h0hB, h0lB, h1hA, h1lA, h1hB, h1lB,
            nullptr, bar_g, aid, m0, j0, smem);
}

// ---------------- FC head (fp32, proven) ----------------

template <int MODE>
__global__ __launch_bounds__(256) void gemm_step(
    const float* __restrict__ A1, int lda1, int K1, const float* __restrict__ W1,
    const float* __restrict__ A2, int K2, const float* __restrict__ W2,
    const float* __restrict__ b1, const float* __restrict__ b2,
    const float* __restrict__ c_in, float* __restrict__ c_out,
    float* __restrict__ h_out)
{
    __shared__ float sA[16][33];
    __shared__ float sW[128][33];

    const int tid = threadIdx.x;
    const int tj  = tid & 31;
    const int tg  = tid >> 5;
    const int m0  = blockIdx.x * 16;
    const int j0  = blockIdx.y * ((MODE == 0) ? 32 : 128);

    float acc[2][4] = {{0.f, 0.f, 0.f, 0.f}, {0.f, 0.f, 0.f, 0.f}};

    for (int seg = 0; seg < 2; ++seg) {
        const float* A  = seg ? A2 : A1;
        const float* W  = seg ? W2 : W1;
        const int    K  = seg ? K2 : K1;
        const int    ld = seg ? HH : lda1;
        if (K == 0) continue;
        for (int kb = 0; kb < K; kb += 32) {
            __syncthreads();
            {
                int idxq = tid;
#pragma unroll
                for (int r = 0; r < 2; ++r, idxq += 256) {
                    int row = idxq >> 5, col = idxq & 31;
                    sA[row][col] = A[(m0 + row) * ld + kb + col];
                }
            }
            {
#pragma unroll
                for (int i = 0; i < 16; ++i) {
                    int idxq = i * 256 + tid;
                    int row = idxq >> 5, col = idxq & 31;
                    int grw;
                    if (MODE == 0) grw = (row >> 5) * HH + j0 + (row & 31);
                    else           grw = j0 + row;
                    sW[row][col] = W[grw * K + kb + col];
                }
            }
            __syncthreads();
#pragma unroll
            for (int k = 0; k < 32; ++k) {
                float a0 = sA[tg][k];
                float a1 = sA[tg + 8][k];
                float w0 = sW[tj][k];
                float w1 = sW[32 + tj][k];
                float w2 = sW[64 + tj][k];
                float w3 = sW[96 + tj][k];
                acc[0][0] += a0 * w0; acc[0][1] += a0 * w1;
                acc[0][2] += a0 * w2; acc[0][3] += a0 * w3;
                acc[1][0] += a1 * w0; acc[1][1] += a1 * w1;
                acc[1][2] += a1 * w2; acc[1][3] += a1 * w3;
            }
        }
    }

    if (MODE == 0) {
        const int j = j0 + tj;
        const float bi = b1[j] + b2[j];
        const float bf = b1[HH + j] + b2[HH + j];
        const float bg = b1[2 * HH + j] + b2[2 * HH + j];
        const float bo = b1[3 * HH + j] + b2[3 * HH + j];
#pragma unroll
        for (int r = 0; r < 2; ++r) {
            int m = m0 + tg + r * 8;
            float gi = acc[r][0] + bi;
            float gf = acc[r][1] + bf;
            float gg = acc[r][2] + bg;
            float go = acc[r][3] + bo;
            float cp = c_in[m * HH + j];
            float c  = sigm(gf) * cp + sigm(gi) * tanhf(gg);
            float h  = sigm(go) * tanhf(c);
            c_out[m * HH + j] = c;
            h_out[m * HH + j] = h;
        }
    } else {
#pragma unroll
        for (int r = 0; r < 2; ++r) {
            int m = m0 + tg + r * 8;
#pragma unroll
            for (int q = 0; q < 4; ++q) {
                int nn = j0 + q * 32 + tj;
                float v = acc[r][q] + b1[nn];
                h_out[m * HH + nn] = fmaxf(v, 0.f);
            }
        }
    }
}

__global__ __launch_bounds__(64) void fc2_kernel(
    const float* __restrict__ z, const float* __restrict__ W,
    const float* __restrict__ b, float* __restrict__ out)
{
    int m = blockIdx.x;
    int lane = threadIdx.x;
    float zr[8];
#pragma unroll
    for (int u = 0; u < 8; ++u) zr[u] = z[m * 512 + u * 64 + lane];
#pragma unroll
    for (int o = 0; o < 8; ++o) {
        float s = 0.f;
#pragma unroll
        for (int u = 0; u < 8; ++u) s += zr[u] * W[o * 512 + u * 64 + lane];
#pragma unroll
        for (int off = 32; off > 0; off >>= 1) s += __shfl_down(s, off);
        if (lane == 0) out[m * 8 + o] = s + b[o];
    }
}

__global__ __launch_bounds__(256) void zero_f_kernel(float* p, int n)
{
    int i = blockIdx.x * 256 + threadIdx.x;
    if (i < n) p[i] = 0.f;
}

// ---------------- host ----------------

extern "C" void kernel_launch(void* const* d_in, const int* in_sizes, int n_in,
                              void* d_out, int out_size, void* d_ws, size_t ws_size,
                              hipStream_t stream)
{
    const float* x     = (const float*)d_in[0];
    const float* W_ih0 = (const float*)d_in[1];
    const float* W_hh0 = (const float*)d_in[2];
    const float* b_ih0 = (const float*)d_in[3];
    const float* b_hh0 = (const float*)d_in[4];
    const float* W_ih1 = (const float*)d_in[5];
    const float* W_hh1 = (const float*)d_in[6];
    const float* b_ih1 = (const float*)d_in[7];
    const float* b_hh1 = (const float*)d_in[8];
    const float* W_fc1 = (const float*)d_in[9];
    const float* b_fc1 = (const float*)d_in[10];
    const float* W_fc2 = (const float*)d_in[11];
    const float* b_fc2 = (const float*)d_in[12];
    float* out = (float*)d_out;

    const size_t S  = (size_t)BB * HH;        // 131072 elems
    const size_t SB = S * sizeof(u16);        // 262144 B
    const size_t SF = S * sizeof(float);      // 524288 B
    const size_t XN = (size_t)BB * TLEN * DD; // 8388608

    const size_t ZERO = 4 * SB + 2 * SF + 4096;   // h bufs + pads + 4KB barriers
    const size_t NEED = ZERO +
                        4 * SB /*other h bufs*/ +
                        2 * SF /*h1last,zfc*/ + 2 * XN * 2 /*x split*/ +
                        2 * 131072 * 2 /*Wih0*/ + 3 * 2 * 1048576 * 2 /*Whh0,Wih1,Whh1*/;

    if (ws_size >= NEED) {
        char* W = (char*)d_ws;
        size_t o = 0;
        u16 *h0hi[2], *h0lo[2], *h1hi[2], *h1lo[2];
        // zero region first: initial-parity h bufs, pads, barriers
        h0hi[0] = (u16*)(W + o); o += SB;
        h0lo[0] = (u16*)(W + o); o += SB;
        h1hi[1] = (u16*)(W + o); o += SB;
        h1lo[1] = (u16*)(W + o); o += SB;
        float* pad0 = (float*)(W + o); o += SF;   // layout stability
        float* pad1 = (float*)(W + o); o += SF;
        unsigned* bar = (unsigned*)(W + o); o += 4096;   // 4 groups x 1KB (subs/top/gen)
        (void)pad0; (void)pad1;
        // rest
        h0hi[1] = (u16*)(W + o); o += SB;
        h0lo[1] = (u16*)(W + o); o += SB;
        h1hi[0] = (u16*)(W + o); o += SB;
        h1lo[0] = (u16*)(W + o); o += SB;
        float* h1last = (float*)(W + o); o += SF;
        float* zfc    = (float*)(W + o); o += SF;
        u16* xhi = (u16*)(W + o); o += XN * 2;
        u16* xlo = (u16*)(W + o); o += XN * 2;
        u16* wih0h = (u16*)(W + o); o += 131072 * 2;
        u16* wih0l = (u16*)(W + o); o += 131072 * 2;
        u16* whh0h = (u16*)(W + o); o += 1048576 * 2;
        u16* whh0l = (u16*)(W + o); o += 1048576 * 2;
        u16* wih1h = (u16*)(W + o); o += 1048576 * 2;
        u16* wih1l = (u16*)(W + o); o += 1048576 * 2;
        u16* whh1h = (u16*)(W + o); o += 1048576 * 2;
        u16* whh1l = (u16*)(W + o); o += 1048576 * 2;

        // zero-init: (2MB + 4KB)/4 = 525312 u32 -> 2052 blocks x 256
        zero_kernel<<<2052, 256, 0, stream>>>((unsigned*)d_ws, (int)(ZERO / 4));
        // splits
        split_kernel<<<2048, 256, 0, stream>>>(x, xhi, xlo, (int)XN);
        split_kernel<<<512, 256, 0, stream>>>(W_ih0, wih0h, wih0l, 131072);
        split_kernel<<<2048, 256, 0, stream>>>(W_hh0, whh0h, whh0l, 1048576);
        split_kernel<<<2048, 256, 0, stream>>>(W_ih1, wih1h, wih1l, 1048576);
        split_kernel<<<2048, 256, 0, stream>>>(W_hh1, whh1h, whh1l, 1048576);

        lstm_persistent<<<256, 512, 0, stream>>>(
            xhi, xlo,
            wih0h, wih0l, whh0h, whh0l,
            wih1h, wih1l, whh1h, whh1l,
            b_ih0, b_hh0, b_ih1, b_hh1,
            h0hi[0], h0lo[0], h0hi[1], h0lo[1],
            h1hi[0], h1lo[0], h1hi[1], h1lo[1],
            h1last, bar);

        dim3 grid_fc1(BB / 16, 512 / 128);
        gemm_step<1><<<grid_fc1, 256, 0, stream>>>(
            h1last, HH, HH, W_fc1, nullptr, 0, nullptr,
            b_fc1, nullptr, nullptr, nullptr, zfc);
        fc2_kernel<<<BB, 64, 0, stream>>>(zfc, W_fc2, b_fc2, out);
        return;
    }

    // -------- fallback: fp32 path (needs ~3.7 MB ws) --------
    float* wsf = (float*)d_ws;
    float* h0a = wsf + 0 * S;
    float* c0  = wsf + 1 * S;
    float* h1a = wsf + 2 * S;
    float* c1  = wsf + 3 * S;
    float* h0b = wsf + 4 * S;
    float* h1b = wsf + 5 * S;
    float* zb  = wsf + 6 * S;
    float* h0buf[2] = {h0a, h0b};
    float* h1buf[2] = {h1a, h1b};

    zero_f_kernel<<<(int)((4 * S + 255) / 256), 256, 0, stream>>>(wsf, (int)(4 * S));

    dim3 grid_lstm(BB / 16, HH / 32);
    for (int t = 0; t < TLEN; ++t) {
        const float* xt = x + (size_t)t * DD;
        gemm_step<0><<<grid_lstm, 256, 0, stream>>>(
            xt, TLEN * DD, DD, W_ih0,
            h0buf[t & 1], HH, W_hh0,
            b_ih0, b_hh0, c0, c0, h0buf[(t + 1) & 1]);
        gemm_step<0><<<grid_lstm, 256, 0, stream>>>(
            h0buf[(t + 1) & 1], HH, HH, W_ih1,
            h1buf[t & 1], HH, W_hh1,
            b_ih1, b_hh1, c1, c1, h1buf[(t + 1) & 1]);
    }
    dim3 grid_fc1(BB / 16, 512 / 128);
    gemm_step<1><<<grid_fc1, 256, 0, stream>>>(
        h1buf[0], HH, HH, W_fc1, nullptr, 0, nullptr,
        b_fc1, nullptr, nullptr, nullptr, zb);
    fc2_kernel<<<BB, 64, 0, stream>>>(zb, W_fc2, b_fc2, out);
}

// Round 7
// 9115.252 us; speedup vs baseline: 1.8748x; 1.8748x over previous
//
#include <hip/hip_runtime.h>
#include <math.h>

typedef unsigned short u16;
typedef __attribute__((ext_vector_type(8))) short short8;
typedef __attribute__((ext_vector_type(4))) float float4v;

#define HH   512
#define BB   256
#define TLEN 512
#define DD   64

__device__ __forceinline__ float sigm(float x) { return 1.0f / (1.0f + __expf(-x)); }

__device__ __forceinline__ u16 bf16rn(float v) {
    unsigned u = __float_as_uint(v);
    u += 0x7fffu + ((u >> 16) & 1u);
    return (u16)(u >> 16);
}
__device__ __forceinline__ float bf16tf(u16 h) { return __uint_as_float(((unsigned)h) << 16); }

// ---------------- precompute kernels ----------------

__global__ __launch_bounds__(256) void split_kernel(const float* __restrict__ src,
                                                    u16* __restrict__ hi, u16* __restrict__ lo, int n)
{
    for (int i = blockIdx.x * 256 + threadIdx.x; i < n; i += gridDim.x * 256) {
        float v = src[i];
        u16 h = bf16rn(v);
        hi[i] = h;
        lo[i] = bf16rn(v - bf16tf(h));
    }
}

__global__ __launch_bounds__(256) void zero_kernel(unsigned* p, int n)
{
    int i = blockIdx.x * 256 + threadIdx.x;
    if (i < n) p[i] = 0u;
}

// ---------------- persistent fused LSTM ----------------
// Round-7 = round-4 compute (proven 7.32 ms, VGPR 128, NO spill) + the
// round-5/6 TREE barrier (proven correct twice; round-5/6 slowness was
// register spill in their compute path, not the barrier).
// Lesson from rounds 5/6: 512-thread kernels compile to a 128-VGPR arch
// budget in this toolchain regardless of __launch_bounds__; any structure
// demanding more spills ~30 regs -> 16 MB/step scratch writeback. Round-4's
// compute fits; do not touch it.
// Barrier math: round-4's single 64-arrival counter = 64 SERIALIZED
// cross-XCD RMWs (~150-400ns each) per step ~= 5-8us/step. Tree: 8 sub-
// counters (8 arrivals each) + 8-wide top -> 2 serialized levels.

template<int NKT, int C1, bool ROLE1>
__device__ void lstm_body(
    const u16* __restrict__ X1h, const u16* __restrict__ X1l,
    const u16* __restrict__ B1h, const u16* __restrict__ B1l, const int ldb1,
    const u16* __restrict__ B2h, const u16* __restrict__ B2l,
    const float* __restrict__ pbi, const float* __restrict__ pbh,
    u16* __restrict__ h0hA, u16* __restrict__ h0lA,
    u16* __restrict__ h0hB, u16* __restrict__ h0lB,
    u16* __restrict__ h1hA, u16* __restrict__ h1lA,
    u16* __restrict__ h1hB, u16* __restrict__ h1lB,
    float* __restrict__ h1last,
    unsigned* bar_g, const int aid,
    const int m0, const int j0, u16* smem)
{
    const int tid  = threadIdx.x;
    const int lane = tid & 63;
    const int wv   = tid >> 6;
    const int g    = wv & 3;
    const int kh   = wv >> 2;
    float* sX = (float*)smem;   // [8][64][18] f32 exchange, aliases staging (sync'd)

    // ---- B slice -> registers/scratch, once (kh half of K, gate g, 16 j-cols) ----
    short8 rBh[NKT], rBl[NKT];
    {
        const size_t brow = (size_t)(g * HH + j0 + (lane & 15));
        const int kq = (lane >> 4) * 8;
#pragma unroll
        for (int i = 0; i < NKT; ++i) {
            const int kt = kh * NKT + i;
            const u16 *ph, *pl;
            if (kt < C1) {
                ph = B1h + brow * (size_t)ldb1 + kt * 32 + kq;
                pl = B1l + brow * (size_t)ldb1 + kt * 32 + kq;
            } else {
                ph = B2h + brow * HH + (size_t)(kt - C1) * 32 + kq;
                pl = B2l + brow * HH + (size_t)(kt - C1) * 32 + kq;
            }
            rBh[i] = *(const short8*)ph;
            rBl[i] = *(const short8*)pl;
        }
    }

    // ---- staging constants: 2 x 16B per thread per chunk (16 KB/buffer) ----
    // tile (half,hl): 64 rows x 32k u16; row = 64B; 16B-slot XOR swizzle.
    int r_[2], ks_[2], hl_[2], half_[2], loff_[2];
#pragma unroll
    for (int q = 0; q < 2; ++q) {
        const int idx  = q * 512 + tid;
        const int tile = idx >> 8;          // 0..3 = half*2 + hilo
        half_[q] = tile >> 1;
        hl_[q]   = tile & 1;
        const int t8 = idx & 255;
        const int r  = t8 >> 2;
        const int k3 = t8 & 3;
        r_[q]  = r;
        ks_[q] = k3 * 8;                    // global k sub-offset (unswizzled)
        loff_[q] = tile * 2048 + r * 32 + ((k3 ^ ((r >> 1) & 3)) * 8);
    }

    // ---- A-frag read offsets (swizzled; row = mt*16 + cR, mt*16 keeps swizzle) ----
    const int cR = lane & 15, q4 = lane >> 4;
    const int abase = kh * 4096 + cR * 32 + ((q4 ^ ((cR >> 1) & 3)) * 8);

    // ---- epilogue constants ----
    const int jj  = j0 + (tid & 15);
    const int mb2 = (tid >> 4) * 2;
    const float bI = pbi[jj] + pbh[jj];
    const float bF = pbi[HH + jj] + pbh[HH + jj];
    const float bG = pbi[2 * HH + jj] + pbh[2 * HH + jj];
    const float bO = pbi[3 * HH + jj] + pbh[3 * HH + jj];
    float cst0 = 0.f, cst1 = 0.f;           // c-state in registers

    unsigned* subp = bar_g + (aid >> 3) * 16;   // 8 sub-counters, 64B apart
    unsigned* topp = bar_g + 128;
    unsigned* genp = bar_g + 144;

    for (int n = 0; n <= TLEN; ++n) {
        const int rb = n & 1;
        const bool active = ROLE1 ? (n > 0) : (n < TLEN);
        if (active) {
            const u16 *A1h_, *A1l_, *A2h_, *A2l_;
            u16 *wh, *wl;
            size_t ld1;
            if (ROLE1) {
                A1h_ = rb ? h0hB : h0hA; A1l_ = rb ? h0lB : h0lA;
                A2h_ = rb ? h1hB : h1hA; A2l_ = rb ? h1lB : h1lA;
                wh   = rb ? h1hA : h1hB; wl   = rb ? h1lA : h1lB;
                ld1 = HH;
            } else {
                A1h_ = X1h + (size_t)n * DD; A1l_ = X1l + (size_t)n * DD;
                A2h_ = rb ? h0hB : h0hA;     A2l_ = rb ? h0lB : h0lA;
                wh   = rb ? h0hA : h0hB;     wl   = rb ? h0lA : h0lB;
                ld1 = (size_t)TLEN * DD;
            }

            auto srcp = [&](int kt, int r, int ks, int lo) -> const u16* {
                if (kt < C1) return (lo ? A1l_ : A1h_) + (size_t)(m0 + r) * ld1 + kt * 32 + ks;
                return (lo ? A2l_ : A2h_) + (size_t)(m0 + r) * HH + (size_t)(kt - C1) * 32 + ks;
            };

            float4v acc[4];
#pragma unroll
            for (int mt = 0; mt < 4; ++mt) acc[mt] = (float4v){0.f, 0.f, 0.f, 0.f};

            // ---- depth-2 prefetch pipeline; chunk c lives in reg-set c&1 ----
            short8 vS[2][2];
            vS[0][0] = *(const short8*)srcp(half_[0] * NKT + 0, r_[0], ks_[0], hl_[0]);
            vS[0][1] = *(const short8*)srcp(half_[1] * NKT + 0, r_[1], ks_[1], hl_[1]);
            if (NKT > 1) {
                vS[1][0] = *(const short8*)srcp(half_[0] * NKT + 1, r_[0], ks_[0], hl_[0]);
                vS[1][1] = *(const short8*)srcp(half_[1] * NKT + 1, r_[1], ks_[1], hl_[1]);
            }
            *(short8*)&smem[loff_[0]] = vS[0][0];   // stage chunk 0 -> buf0
            *(short8*)&smem[loff_[1]] = vS[0][1];

#pragma unroll
            for (int i = 0; i < NKT; ++i) {
                __syncthreads();               // buf[i&1] staged; prev reads done
                const int buf = i & 1;
                if (i + 1 < NKT) {             // stage chunk i+1 into buf^1
                    *(short8*)&smem[(buf ^ 1) * 8192 + loff_[0]] = vS[(i + 1) & 1][0];
                    *(short8*)&smem[(buf ^ 1) * 8192 + loff_[1]] = vS[(i + 1) & 1][1];
                }
                if (i + 2 < NKT) {             // issue loads for chunk i+2
                    vS[i & 1][0] = *(const short8*)srcp(half_[0] * NKT + i + 2, r_[0], ks_[0], hl_[0]);
                    vS[i & 1][1] = *(const short8*)srcp(half_[1] * NKT + i + 2, r_[1], ks_[1], hl_[1]);
                }
                const int ab = buf * 8192 + abase;
                short8 aH[4], aL[4];
#pragma unroll
                for (int mt = 0; mt < 4; ++mt) {
                    aH[mt] = *(const short8*)&smem[ab + mt * 512];
                    aL[mt] = *(const short8*)&smem[ab + 2048 + mt * 512];
                }
#pragma unroll
                for (int mt = 0; mt < 4; ++mt) {
                    acc[mt] = __builtin_amdgcn_mfma_f32_16x16x32_bf16(aH[mt], rBh[i], acc[mt], 0, 0, 0);
                    acc[mt] = __builtin_amdgcn_mfma_f32_16x16x32_bf16(aH[mt], rBl[i], acc[mt], 0, 0, 0);
                    acc[mt] = __builtin_amdgcn_mfma_f32_16x16x32_bf16(aL[mt], rBh[i], acc[mt], 0, 0, 0);
                }
            }

            // ---- gate/k-half exchange via LDS ----
            __syncthreads();
#pragma unroll
            for (int mt = 0; mt < 4; ++mt)
#pragma unroll
                for (int r = 0; r < 4; ++r)
                    sX[wv * 1152 + (mt * 16 + (lane >> 4) * 4 + r) * 18 + (lane & 15)] = acc[mt][r];
            __syncthreads();

#pragma unroll
            for (int p = 0; p < 2; ++p) {
                const int m = mb2 + p;
                const int xb = m * 18 + (tid & 15);
                const float gi = sX[0 * 1152 + xb] + sX[4 * 1152 + xb] + bI;
                const float gf = sX[1 * 1152 + xb] + sX[5 * 1152 + xb] + bF;
                const float gg = sX[2 * 1152 + xb] + sX[6 * 1152 + xb] + bG;
                const float go = sX[3 * 1152 + xb] + sX[7 * 1152 + xb] + bO;
                const float cp = p ? cst1 : cst0;
                const float cn = sigm(gf) * cp + sigm(gi) * tanhf(gg);
                const float h  = sigm(go) * tanhf(cn);
                if (p) cst1 = cn; else cst0 = cn;
                const size_t off = (size_t)(m0 + m) * HH + jj;
                const u16 hv = bf16rn(h);
                wh[off] = hv;
                wl[off] = bf16rn(h - bf16tf(hv));
                if (ROLE1 && n == TLEN) h1last[off] = h;
            }
        }

        // ---- inter-block barrier: lockstep gen protocol, TREE arrival ----
        __syncthreads();   // drains vmcnt(0): h stores in L2 before release
        if (tid == 0) {
            const unsigned g0 = __hip_atomic_load(genp, __ATOMIC_RELAXED, __HIP_MEMORY_SCOPE_AGENT);
            const unsigned a = __hip_atomic_fetch_add(subp, 1u, __ATOMIC_ACQ_REL, __HIP_MEMORY_SCOPE_AGENT);
            if (a == 7u) {
                __hip_atomic_store(subp, 0u, __ATOMIC_RELAXED, __HIP_MEMORY_SCOPE_AGENT);
                const unsigned t = __hip_atomic_fetch_add(topp, 1u, __ATOMIC_ACQ_REL, __HIP_MEMORY_SCOPE_AGENT);
                if (t == 7u) {
                    __hip_atomic_store(topp, 0u, __ATOMIC_RELAXED, __HIP_MEMORY_SCOPE_AGENT);
                    __hip_atomic_store(genp, g0 + 1u, __ATOMIC_RELEASE, __HIP_MEMORY_SCOPE_AGENT);
                }
            }
            int sp = 0;
            while (__hip_atomic_load(genp, __ATOMIC_RELAXED, __HIP_MEMORY_SCOPE_AGENT) == g0) {
                __builtin_amdgcn_s_sleep(1);
                if ((++sp & 63) == 0)   // safety net: periodic coherent-forcing poll
                    (void)__hip_atomic_load(genp, __ATOMIC_ACQUIRE, __HIP_MEMORY_SCOPE_AGENT);
            }
            // single acquire: L1/L2 fresh for next step's h reads
            (void)__hip_atomic_load(genp, __ATOMIC_ACQUIRE, __HIP_MEMORY_SCOPE_AGENT);
        }
        __syncthreads();
    }
}

__global__ __launch_bounds__(512, 2) void lstm_persistent(
    const u16* __restrict__ xhi, const u16* __restrict__ xlo,
    const u16* __restrict__ Wih0h, const u16* __restrict__ Wih0l,
    const u16* __restrict__ Whh0h, const u16* __restrict__ Whh0l,
    const u16* __restrict__ Wih1h, const u16* __restrict__ Wih1l,
    const u16* __restrict__ Whh1h, const u16* __restrict__ Whh1l,
    const float* __restrict__ bi0, const float* __restrict__ bh0,
    const float* __restrict__ bi1, const float* __restrict__ bh1,
    u16* h0hA, u16* h0lA, u16* h0hB, u16* h0lB,
    u16* h1hA, u16* h1lA, u16* h1hB, u16* h1lB,
    float* __restrict__ h1last, unsigned* bar)
{
    __shared__ u16 smem[18432];   // 32KB staging (2 bufs) / 36.9KB exchange (aliased)
    const bool role1 = (blockIdx.x >= 128);
    const int idx = blockIdx.x & 127;
    const int m0 = (idx & 3) * 64;
    const int j0 = (idx >> 2) * 16;
    const int gid = idx & 3;
    unsigned* bar_g = bar + gid * 256;              // 1 KB per m-group
    const int aid = (role1 ? 32 : 0) + (idx >> 2);  // arrival id 0..63

    if (role1)
        lstm_body<16, 16, true>(nullptr, nullptr,
            Wih1h, Wih1l, HH, Whh1h, Whh1l, bi1, bh1,
            h0hA, h0lA, h0hB, h0lB, h1hA, h1lA, h1hB, h1lB,
            h1last, bar_g, aid, m0, j0, smem);
    else
        lstm_body<9, 2, false>(xhi, xlo,
            Wih0h, Wih0l, DD, Whh0h, Whh0l, bi0, bh0,
            h0hA, h0lA, h0hB, h0lB, h1hA, h1lA, h1hB, h1lB,
            nullptr, bar_g, aid, m0, j0, smem);
}

// ---------------- FC head (fp32, proven) ----------------

template <int MODE>
__global__ __launch_bounds__(256) void gemm_step(
    const float* __restrict__ A1, int lda1, int K1, const float* __restrict__ W1,
    const float* __restrict__ A2, int K2, const float* __restrict__ W2,
    const float* __restrict__ b1, const float* __restrict__ b2,
    const float* __restrict__ c_in, float* __restrict__ c_out,
    float* __restrict__ h_out)
{
    __shared__ float sA[16][33];
    __shared__ float sW[128][33];

    const int tid = threadIdx.x;
    const int tj  = tid & 31;
    const int tg  = tid >> 5;
    const int m0  = blockIdx.x * 16;
    const int j0  = blockIdx.y * ((MODE == 0) ? 32 : 128);

    float acc[2][4] = {{0.f, 0.f, 0.f, 0.f}, {0.f, 0.f, 0.f, 0.f}};

    for (int seg = 0; seg < 2; ++seg) {
        const float* A  = seg ? A2 : A1;
        const float* W  = seg ? W2 : W1;
        const int    K  = seg ? K2 : K1;
        const int    ld = seg ? HH : lda1;
        if (K == 0) continue;
        for (int kb = 0; kb < K; kb += 32) {
            __syncthreads();
            {
                int idxq = tid;
#pragma unroll
                for (int r = 0; r < 2; ++r, idxq += 256) {
                    int row = idxq >> 5, col = idxq & 31;
                    sA[row][col] = A[(m0 + row) * ld + kb + col];
                }
            }
            {
#pragma unroll
                for (int i = 0; i < 16; ++i) {
                    int idxq = i * 256 + tid;
                    int row = idxq >> 5, col = idxq & 31;
                    int grw;
                    if (MODE == 0) grw = (row >> 5) * HH + j0 + (row & 31);
                    else           grw = j0 + row;
                    sW[row][col] = W[grw * K + kb + col];
                }
            }
            __syncthreads();
#pragma unroll
            for (int k = 0; k < 32; ++k) {
                float a0 = sA[tg][k];
                float a1 = sA[tg + 8][k];
                float w0 = sW[tj][k];
                float w1 = sW[32 + tj][k];
                float w2 = sW[64 + tj][k];
                float w3 = sW[96 + tj][k];
                acc[0][0] += a0 * w0; acc[0][1] += a0 * w1;
                acc[0][2] += a0 * w2; acc[0][3] += a0 * w3;
                acc[1][0] += a1 * w0; acc[1][1] += a1 * w1;
                acc[1][2] += a1 * w2; acc[1][3] += a1 * w3;
            }
        }
    }

    if (MODE == 0) {
        const int j = j0 + tj;
        const float bi = b1[j] + b2[j];
        const float bf = b1[HH + j] + b2[HH + j];
        const float bg = b1[2 * HH + j] + b2[2 * HH + j];
        const float bo = b1[3 * HH + j] + b2[3 * HH + j];
#pragma unroll
        for (int r = 0; r < 2; ++r) {
            int m = m0 + tg + r * 8;
            float gi = acc[r][0] + bi;
            float gf = acc[r][1] + bf;
            float gg = acc[r][2] + bg;
            float go = acc[r][3] + bo;
            float cp = c_in[m * HH + j];
            float c  = sigm(gf) * cp + sigm(gi) * tanhf(gg);
            float h  = sigm(go) * tanhf(c);
            c_out[m * HH + j] = c;
            h_out[m * HH + j] = h;
        }
    } else {
#pragma unroll
        for (int r = 0; r < 2; ++r) {
            int m = m0 + tg + r * 8;
#pragma unroll
            for (int q = 0; q < 4; ++q) {
                int nn = j0 + q * 32 + tj;
                float v = acc[r][q] + b1[nn];
                h_out[m * HH + nn] = fmaxf(v, 0.f);
            }
        }
    }
}

__global__ __launch_bounds__(64) void fc2_kernel(
    const float* __restrict__ z, const float* __restrict__ W,
    const float* __restrict__ b, float* __restrict__ out)
{
    int m = blockIdx.x;
    int lane = threadIdx.x;
    float zr[8];
#pragma unroll
    for (int u = 0; u < 8; ++u) zr[u] = z[m * 512 + u * 64 + lane];
#pragma unroll
    for (int o = 0; o < 8; ++o) {
        float s = 0.f;
#pragma unroll
        for (int u = 0; u < 8; ++u) s += zr[u] * W[o * 512 + u * 64 + lane];
#pragma unroll
        for (int off = 32; off > 0; off >>= 1) s += __shfl_down(s, off);
        if (lane == 0) out[m * 8 + o] = s + b[o];
    }
}

__global__ __launch_bounds__(256) void zero_f_kernel(float* p, int n)
{
    int i = blockIdx.x * 256 + threadIdx.x;
    if (i < n) p[i] = 0.f;
}

// ---------------- host ----------------

extern "C" void kernel_launch(void* const* d_in, const int* in_sizes, int n_in,
                              void* d_out, int out_size, void* d_ws, size_t ws_size,
                              hipStream_t stream)
{
    const float* x     = (const float*)d_in[0];
    const float* W_ih0 = (const float*)d_in[1];
    const float* W_hh0 = (const float*)d_in[2];
    const float* b_ih0 = (const float*)d_in[3];
    const float* b_hh0 = (const float*)d_in[4];
    const float* W_ih1 = (const float*)d_in[5];
    const float* W_hh1 = (const float*)d_in[6];
    const float* b_ih1 = (const float*)d_in[7];
    const float* b_hh1 = (const float*)d_in[8];
    const float* W_fc1 = (const float*)d_in[9];
    const float* b_fc1 = (const float*)d_in[10];
    const float* W_fc2 = (const float*)d_in[11];
    const float* b_fc2 = (const float*)d_in[12];
    float* out = (float*)d_out;

    const size_t S  = (size_t)BB * HH;        // 131072 elems
    const size_t SB = S * sizeof(u16);        // 262144 B
    const size_t SF = S * sizeof(float);      // 524288 B
    const size_t XN = (size_t)BB * TLEN * DD; // 8388608

    const size_t ZERO = 4 * SB + 2 * SF + 4096;   // h bufs + pads + 4KB barriers
    const size_t NEED = ZERO +
                        4 * SB /*other h bufs*/ +
                        2 * SF /*h1last,zfc*/ + 2 * XN * 2 /*x split*/ +
                        2 * 131072 * 2 /*Wih0*/ + 3 * 2 * 1048576 * 2 /*Whh0,Wih1,Whh1*/;

    if (ws_size >= NEED) {
        char* W = (char*)d_ws;
        size_t o = 0;
        u16 *h0hi[2], *h0lo[2], *h1hi[2], *h1lo[2];
        // zero region first: initial-parity h bufs, pads, barriers
        h0hi[0] = (u16*)(W + o); o += SB;
        h0lo[0] = (u16*)(W + o); o += SB;
        h1hi[1] = (u16*)(W + o); o += SB;
        h1lo[1] = (u16*)(W + o); o += SB;
        float* pad0 = (float*)(W + o); o += SF;   // layout stability
        float* pad1 = (float*)(W + o); o += SF;
        unsigned* bar = (unsigned*)(W + o); o += 4096;   // 4 groups x 1KB (subs/top/gen)
        (void)pad0; (void)pad1;
        // rest
        h0hi[1] = (u16*)(W + o); o += SB;
        h0lo[1] = (u16*)(W + o); o += SB;
        h1hi[0] = (u16*)(W + o); o += SB;
        h1lo[0] = (u16*)(W + o); o += SB;
        float* h1last = (float*)(W + o); o += SF;
        float* zfc    = (float*)(W + o); o += SF;
        u16* xhi = (u16*)(W + o); o += XN * 2;
        u16* xlo = (u16*)(W + o); o += XN * 2;
        u16* wih0h = (u16*)(W + o); o += 131072 * 2;
        u16* wih0l = (u16*)(W + o); o += 131072 * 2;
        u16* whh0h = (u16*)(W + o); o += 1048576 * 2;
        u16* whh0l = (u16*)(W + o); o += 1048576 * 2;
        u16* wih1h = (u16*)(W + o); o += 1048576 * 2;
        u16* wih1l = (u16*)(W + o); o += 1048576 * 2;
        u16* whh1h = (u16*)(W + o); o += 1048576 * 2;
        u16* whh1l = (u16*)(W + o); o += 1048576 * 2;

        // zero-init: (2MB + 4KB)/4 = 525312 u32 -> 2052 blocks x 256
        zero_kernel<<<2052, 256, 0, stream>>>((unsigned*)d_ws, (int)(ZERO / 4));
        // splits
        split_kernel<<<2048, 256, 0, stream>>>(x, xhi, xlo, (int)XN);
        split_kernel<<<512, 256, 0, stream>>>(W_ih0, wih0h, wih0l, 131072);
        split_kernel<<<2048, 256, 0, stream>>>(W_hh0, whh0h, whh0l, 1048576);
        split_kernel<<<2048, 256, 0, stream>>>(W_ih1, wih1h, wih1l, 1048576);
        split_kernel<<<2048, 256, 0, stream>>>(W_hh1, whh1h, whh1l, 1048576);

        lstm_persistent<<<256, 512, 0, stream>>>(
            xhi, xlo,
            wih0h, wih0l, whh0h, whh0l,
            wih1h, wih1l, whh1h, whh1l,
            b_ih0, b_hh0, b_ih1, b_hh1,
            h0hi[0], h0lo[0], h0hi[1], h0lo[1],
            h1hi[0], h1lo[0], h1hi[1], h1lo[1],
            h1last, bar);

        dim3 grid_fc1(BB / 16, 512 / 128);
        gemm_step<1><<<grid_fc1, 256, 0, stream>>>(
            h1last, HH, HH, W_fc1, nullptr, 0, nullptr,
            b_fc1, nullptr, nullptr, nullptr, zfc);
        fc2_kernel<<<BB, 64, 0, stream>>>(zfc, W_fc2, b_fc2, out);
        return;
    }

    // -------- fallback: fp32 path (needs ~3.7 MB ws) --------
    float* wsf = (float*)d_ws;
    float* h0a = wsf + 0 * S;
    float* c0  = wsf + 1 * S;
    float* h1a = wsf + 2 * S;
    float* c1  = wsf + 3 * S;
    float* h0b = wsf + 4 * S;
    float* h1b = wsf + 5 * S;
    float* zb  = wsf + 6 * S;
    float* h0buf[2] = {h0a, h0b};
    float* h1buf[2] = {h1a, h1b};

    zero_f_kernel<<<(int)((4 * S + 255) / 256), 256, 0, stream>>>(wsf, (int)(4 * S));

    dim3 grid_lstm(BB / 16, HH / 32);
    for (int t = 0; t < TLEN; ++t) {
        const float* xt = x + (size_t)t * DD;
        gemm_step<0><<<grid_lstm, 256, 0, stream>>>(
            xt, TLEN * DD, DD, W_ih0,
            h0buf[t & 1], HH, W_hh0,
            b_ih0, b_hh0, c0, c0, h0buf[(t + 1) & 1]);
        gemm_step<0><<<grid_lstm, 256, 0, stream>>>(
            h0buf[(t + 1) & 1], HH, HH, W_ih1,
            h1buf[t & 1], HH, W_hh1,
            b_ih1, b_hh1, c1, c1, h1buf[(t + 1) & 1]);
    }
    dim3 grid_fc1(BB / 16, 512 / 128);
    gemm_step<1><<<grid_fc1, 256, 0, stream>>>(
        h1buf[0], HH, HH, W_fc1, nullptr, 0, nullptr,
        b_fc1, nullptr, nullptr, nullptr, zb);
    fc2_kernel<<<BB, 64, 0, stream>>>(zb, W_fc2, b_fc2, out);
}

// Round 8
// 8388.734 us; speedup vs baseline: 2.0372x; 1.0866x over previous
//
#include <hip/hip_runtime.h>
#include <math.h>

typedef unsigned short u16;
typedef __attribute__((ext_vector_type(8))) short short8;
typedef __attribute__((ext_vector_type(4))) float float4v;

#define HH   512
#define BB   256
#define TLEN 512
#define DD   64

__device__ __forceinline__ float sigm(float x) { return 1.0f / (1.0f + __expf(-x)); }

__device__ __forceinline__ u16 bf16rn(float v) {
    unsigned u = __float_as_uint(v);
    u += 0x7fffu + ((u >> 16) & 1u);
    return (u16)(u >> 16);
}
__device__ __forceinline__ float bf16tf(u16 h) { return __uint_as_float(((unsigned)h) << 16); }

template <typename T>
__device__ __forceinline__ T sel3(int i, T a, T b, T c) { return i == 0 ? a : (i == 1 ? b : c); }

// ---------------- precompute kernels ----------------

__global__ __launch_bounds__(256) void split_kernel(const float* __restrict__ src,
                                                    u16* __restrict__ hi, u16* __restrict__ lo, int n)
{
    for (int i = blockIdx.x * 256 + threadIdx.x; i < n; i += gridDim.x * 256) {
        float v = src[i];
        u16 h = bf16rn(v);
        hi[i] = h;
        lo[i] = bf16rn(v - bf16tf(h));
    }
}

__global__ __launch_bounds__(256) void zero_kernel(unsigned* p, int n)
{
    int i = blockIdx.x * 256 + threadIdx.x;
    if (i < n) p[i] = 0u;
}

// ---------------- persistent fused LSTM ----------------
// Round-8 = round-4 compute VERBATIM (proven 7.32 ms, no spill) + DECOUPLED
// role sync. Round-7 lesson: tree barrier is SLOWER than flat same-line
// atomics (dependent RMW depth >> same-line RMW throughput). Round-4 lesson:
// lockstep couples both roles to max(role0,role1)+barrier(64) per step.
// New sync: per m-group, two 32-wide monotonic arrival counters.
//   role0 iter n: wait bc0>=32n (own group) && bc1>=32(n-1) (h0 buf free)
//   role1 iter n: wait bc1>=32n (own group) && bc0>=32n  (h0[n-1] ready)
//   arrive: fetch_add(own, 1, RELEASE) after vmcnt-draining syncthreads.
// h0 TRIPLE-buffered (write n%3, read (n+2)%3) so role0 runs 1 iter ahead;
// role1's wait on bc0 is then pre-satisfied -> critical path = own 32 group.
// Poll with relaxed LOADS (round-3 polled with fetch_add(+0) RMWs - each
// poller steals the line exclusively; suspected livelock). Periodic + final
// ACQUIRE = the round-2/4-proven freshness pattern.

template<int NKT, int C1, bool ROLE1>
__device__ void lstm_body(
    const u16* __restrict__ X1h, const u16* __restrict__ X1l,
    const u16* __restrict__ B1h, const u16* __restrict__ B1l, const int ldb1,
    const u16* __restrict__ B2h, const u16* __restrict__ B2l,
    const float* __restrict__ pbi, const float* __restrict__ pbh,
    u16* __restrict__ h0h0, u16* __restrict__ h0l0,
    u16* __restrict__ h0h1, u16* __restrict__ h0l1,
    u16* __restrict__ h0h2, u16* __restrict__ h0l2,
    u16* __restrict__ h1hA, u16* __restrict__ h1lA,
    u16* __restrict__ h1hB, u16* __restrict__ h1lB,
    float* __restrict__ h1last,
    unsigned* bc0, unsigned* bc1,
    const int m0, const int j0, u16* smem)
{
    const int tid  = threadIdx.x;
    const int lane = tid & 63;
    const int wv   = tid >> 6;
    const int g    = wv & 3;
    const int kh   = wv >> 2;
    float* sX = (float*)smem;   // [8][64][18] f32 exchange, aliases staging (sync'd)

    // ---- B slice -> registers, once (kh half of K, gate g, 16 j-cols) ----
    short8 rBh[NKT], rBl[NKT];
    {
        const size_t brow = (size_t)(g * HH + j0 + (lane & 15));
        const int kq = (lane >> 4) * 8;
#pragma unroll
        for (int i = 0; i < NKT; ++i) {
            const int kt = kh * NKT + i;
            const u16 *ph, *pl;
            if (kt < C1) {
                ph = B1h + brow * (size_t)ldb1 + kt * 32 + kq;
                pl = B1l + brow * (size_t)ldb1 + kt * 32 + kq;
            } else {
                ph = B2h + brow * HH + (size_t)(kt - C1) * 32 + kq;
                pl = B2l + brow * HH + (size_t)(kt - C1) * 32 + kq;
            }
            rBh[i] = *(const short8*)ph;
            rBl[i] = *(const short8*)pl;
        }
    }

    // ---- staging constants: 2 x 16B per thread per chunk (16 KB/buffer) ----
    // tile (half,hl): 64 rows x 32k u16; row = 64B; 16B-slot XOR swizzle.
    int r_[2], ks_[2], hl_[2], half_[2], loff_[2];
#pragma unroll
    for (int q = 0; q < 2; ++q) {
        const int idx  = q * 512 + tid;
        const int tile = idx >> 8;          // 0..3 = half*2 + hilo
        half_[q] = tile >> 1;
        hl_[q]   = tile & 1;
        const int t8 = idx & 255;
        const int r  = t8 >> 2;
        const int k3 = t8 & 3;
        r_[q]  = r;
        ks_[q] = k3 * 8;                    // global k sub-offset (unswizzled)
        loff_[q] = tile * 2048 + r * 32 + ((k3 ^ ((r >> 1) & 3)) * 8);
    }

    // ---- A-frag read offsets (swizzled; row = mt*16 + cR, mt*16 keeps swizzle) ----
    const int cR = lane & 15, q4 = lane >> 4;
    const int abase = kh * 4096 + cR * 32 + ((q4 ^ ((cR >> 1) & 3)) * 8);

    // ---- epilogue constants ----
    const int jj  = j0 + (tid & 15);
    const int mb2 = (tid >> 4) * 2;
    const float bI = pbi[jj] + pbh[jj];
    const float bF = pbi[HH + jj] + pbh[HH + jj];
    const float bG = pbi[2 * HH + jj] + pbh[2 * HH + jj];
    const float bO = pbi[3 * HH + jj] + pbh[3 * HH + jj];
    float cst0 = 0.f, cst1 = 0.f;           // c-state in registers

    for (int n = 0; n <= TLEN; ++n) {
        // ---- decoupled wait (relaxed-load poll; acquire once on exit) ----
        if (tid == 0) {
            const unsigned tOwn = 32u * (unsigned)n;
            const unsigned tOth = ROLE1 ? 32u * (unsigned)n
                                        : (n >= 1 ? 32u * (unsigned)(n - 1) : 0u);
            unsigned* own = ROLE1 ? bc1 : bc0;
            unsigned* oth = ROLE1 ? bc0 : bc1;
            int sp = 0;
            for (;;) {
                unsigned vo = __hip_atomic_load(own, __ATOMIC_RELAXED, __HIP_MEMORY_SCOPE_AGENT);
                unsigned vt = __hip_atomic_load(oth, __ATOMIC_RELAXED, __HIP_MEMORY_SCOPE_AGENT);
                if (vo >= tOwn && vt >= tOth) break;
                __builtin_amdgcn_s_sleep(2);
                if ((++sp & 63) == 0)   // safety net: periodic coherent-forcing poll
                    (void)__hip_atomic_load(own, __ATOMIC_ACQUIRE, __HIP_MEMORY_SCOPE_AGENT);
            }
            // single acquire: L1/L2 fresh for this iter's h reads (B is in regs)
            (void)__hip_atomic_load(own, __ATOMIC_ACQUIRE, __HIP_MEMORY_SCOPE_AGENT);
        }
        __syncthreads();

        const bool active = ROLE1 ? (n > 0) : (n < TLEN);
        if (active) {
            const int rb   = n & 1;
            const int rbuf = (n + 2) % 3;   // h0 read buffer (written iter n-1)
            const int wbuf = n % 3;         // h0 write buffer (role0)

            const u16 *A1h_, *A1l_, *A2h_, *A2l_;
            u16 *wh, *wl;
            size_t ld1;
            if (ROLE1) {
                A1h_ = sel3<const u16*>(rbuf, h0h0, h0h1, h0h2);
                A1l_ = sel3<const u16*>(rbuf, h0l0, h0l1, h0l2);
                A2h_ = rb ? h1hB : h1hA; A2l_ = rb ? h1lB : h1lA;
                wh   = rb ? h1hA : h1hB; wl   = rb ? h1lA : h1lB;
                ld1 = HH;
            } else {
                A1h_ = X1h + (size_t)n * DD; A1l_ = X1l + (size_t)n * DD;
                A2h_ = sel3<const u16*>(rbuf, h0h0, h0h1, h0h2);
                A2l_ = sel3<const u16*>(rbuf, h0l0, h0l1, h0l2);
                wh   = sel3<u16*>(wbuf, h0h0, h0h1, h0h2);
                wl   = sel3<u16*>(wbuf, h0l0, h0l1, h0l2);
                ld1 = (size_t)TLEN * DD;
            }

            auto srcp = [&](int kt, int r, int ks, int lo) -> const u16* {
                if (kt < C1) return (lo ? A1l_ : A1h_) + (size_t)(m0 + r) * ld1 + kt * 32 + ks;
                return (lo ? A2l_ : A2h_) + (size_t)(m0 + r) * HH + (size_t)(kt - C1) * 32 + ks;
            };

            float4v acc[4];
#pragma unroll
            for (int mt = 0; mt < 4; ++mt) acc[mt] = (float4v){0.f, 0.f, 0.f, 0.f};

            // ---- depth-2 prefetch pipeline; chunk c lives in reg-set c&1 ----
            short8 vS[2][2];
            vS[0][0] = *(const short8*)srcp(half_[0] * NKT + 0, r_[0], ks_[0], hl_[0]);
            vS[0][1] = *(const short8*)srcp(half_[1] * NKT + 0, r_[1], ks_[1], hl_[1]);
            if (NKT > 1) {
                vS[1][0] = *(const short8*)srcp(half_[0] * NKT + 1, r_[0], ks_[0], hl_[0]);
                vS[1][1] = *(const short8*)srcp(half_[1] * NKT + 1, r_[1], ks_[1], hl_[1]);
            }
            *(short8*)&smem[loff_[0]] = vS[0][0];   // stage chunk 0 -> buf0
            *(short8*)&smem[loff_[1]] = vS[0][1];

#pragma unroll
            for (int i = 0; i < NKT; ++i) {
                __syncthreads();               // buf[i&1] staged; prev reads done
                const int buf = i & 1;
                if (i + 1 < NKT) {             // stage chunk i+1 into buf^1
                    *(short8*)&smem[(buf ^ 1) * 8192 + loff_[0]] = vS[(i + 1) & 1][0];
                    *(short8*)&smem[(buf ^ 1) * 8192 + loff_[1]] = vS[(i + 1) & 1][1];
                }
                if (i + 2 < NKT) {             // issue loads for chunk i+2
                    vS[i & 1][0] = *(const short8*)srcp(half_[0] * NKT + i + 2, r_[0], ks_[0], hl_[0]);
                    vS[i & 1][1] = *(const short8*)srcp(half_[1] * NKT + i + 2, r_[1], ks_[1], hl_[1]);
                }
                const int ab = buf * 8192 + abase;
                short8 aH[4], aL[4];
#pragma unroll
                for (int mt = 0; mt < 4; ++mt) {
                    aH[mt] = *(const short8*)&smem[ab + mt * 512];
                    aL[mt] = *(const short8*)&smem[ab + 2048 + mt * 512];
                }
#pragma unroll
                for (int mt = 0; mt < 4; ++mt) {
                    acc[mt] = __builtin_amdgcn_mfma_f32_16x16x32_bf16(aH[mt], rBh[i], acc[mt], 0, 0, 0);
                    acc[mt] = __builtin_amdgcn_mfma_f32_16x16x32_bf16(aH[mt], rBl[i], acc[mt], 0, 0, 0);
                    acc[mt] = __builtin_amdgcn_mfma_f32_16x16x32_bf16(aL[mt], rBh[i], acc[mt], 0, 0, 0);
                }
            }

            // ---- gate/k-half exchange via LDS ----
            __syncthreads();
#pragma unroll
            for (int mt = 0; mt < 4; ++mt)
#pragma unroll
                for (int r = 0; r < 4; ++r)
                    sX[wv * 1152 + (mt * 16 + (lane >> 4) * 4 + r) * 18 + (lane & 15)] = acc[mt][r];
            __syncthreads();

#pragma unroll
            for (int p = 0; p < 2; ++p) {
                const int m = mb2 + p;
                const int xb = m * 18 + (tid & 15);
                const float gi = sX[0 * 1152 + xb] + sX[4 * 1152 + xb] + bI;
                const float gf = sX[1 * 1152 + xb] + sX[5 * 1152 + xb] + bF;
                const float gg = sX[2 * 1152 + xb] + sX[6 * 1152 + xb] + bG;
                const float go = sX[3 * 1152 + xb] + sX[7 * 1152 + xb] + bO;
                const float cp = p ? cst1 : cst0;
                const float cn = sigm(gf) * cp + sigm(gi) * tanhf(gg);
                const float h  = sigm(go) * tanhf(cn);
                if (p) cst1 = cn; else cst0 = cn;
                const size_t off = (size_t)(m0 + m) * HH + jj;
                const u16 hv = bf16rn(h);
                wh[off] = hv;
                wl[off] = bf16rn(h - bf16tf(hv));
                if (ROLE1 && n == TLEN) h1last[off] = h;
            }
        }

        // ---- arrive: release own-group counter ----
        __syncthreads();   // drains vmcnt(0): h stores in L2 before release
        if (tid == 0)
            __hip_atomic_fetch_add(ROLE1 ? bc1 : bc0, 1u, __ATOMIC_RELEASE, __HIP_MEMORY_SCOPE_AGENT);
        __syncthreads();
    }
}

__global__ __launch_bounds__(512, 2) void lstm_persistent(
    const u16* __restrict__ xhi, const u16* __restrict__ xlo,
    const u16* __restrict__ Wih0h, const u16* __restrict__ Wih0l,
    const u16* __restrict__ Whh0h, const u16* __restrict__ Whh0l,
    const u16* __restrict__ Wih1h, const u16* __restrict__ Wih1l,
    const u16* __restrict__ Whh1h, const u16* __restrict__ Whh1l,
    const float* __restrict__ bi0, const float* __restrict__ bh0,
    const float* __restrict__ bi1, const float* __restrict__ bh1,
    u16* h0h0_, u16* h0l0_, u16* h0h1_, u16* h0l1_, u16* h0h2_, u16* h0l2_,
    u16* h1h0_, u16* h1l0_, u16* h1h1_, u16* h1l1_,
    float* __restrict__ h1last, unsigned* bar)
{
    __shared__ u16 smem[18432];   // 32KB staging (2 bufs) / 36.9KB exchange (aliased)
    const bool role1 = (blockIdx.x >= 128);
    const int idx = blockIdx.x & 127;
    const int m0 = (idx & 3) * 64;
    const int j0 = (idx >> 2) * 16;
    const int gid = idx & 3;
    unsigned* bc0 = bar + gid * 64;        // role0 arrivals (128B-separated lines)
    unsigned* bc1 = bar + gid * 64 + 32;   // role1 arrivals

    if (role1)
        lstm_body<16, 16, true>(nullptr, nullptr,
            Wih1h, Wih1l, HH, Whh1h, Whh1l, bi1, bh1,
            h0h0_, h0l0_, h0h1_, h0l1_, h0h2_, h0l2_,
            h1h0_, h1l0_, h1h1_, h1l1_,
            h1last, bc0, bc1, m0, j0, smem);
    else
        lstm_body<9, 2, false>(xhi, xlo,
            Wih0h, Wih0l, DD, Whh0h, Whh0l, bi0, bh0,
            h0h0_, h0l0_, h0h1_, h0l1_, h0h2_, h0l2_,
            h1h0_, h1l0_, h1h1_, h1l1_,
            nullptr, bc0, bc1, m0, j0, smem);
}

// ---------------- FC head (fp32, proven) ----------------

template <int MODE>
__global__ __launch_bounds__(256) void gemm_step(
    const float* __restrict__ A1, int lda1, int K1, const float* __restrict__ W1,
    const float* __restrict__ A2, int K2, const float* __restrict__ W2,
    const float* __restrict__ b1, const float* __restrict__ b2,
    const float* __restrict__ c_in, float* __restrict__ c_out,
    float* __restrict__ h_out)
{
    __shared__ float sA[16][33];
    __shared__ float sW[128][33];

    const int tid = threadIdx.x;
    const int tj  = tid & 31;
    const int tg  = tid >> 5;
    const int m0  = blockIdx.x * 16;
    const int j0  = blockIdx.y * ((MODE == 0) ? 32 : 128);

    float acc[2][4] = {{0.f, 0.f, 0.f, 0.f}, {0.f, 0.f, 0.f, 0.f}};

    for (int seg = 0; seg < 2; ++seg) {
        const float* A  = seg ? A2 : A1;
        const float* W  = seg ? W2 : W1;
        const int    K  = seg ? K2 : K1;
        const int    ld = seg ? HH : lda1;
        if (K == 0) continue;
        for (int kb = 0; kb < K; kb += 32) {
            __syncthreads();
            {
                int idxq = tid;
#pragma unroll
                for (int r = 0; r < 2; ++r, idxq += 256) {
                    int row = idxq >> 5, col = idxq & 31;
                    sA[row][col] = A[(m0 + row) * ld + kb + col];
                }
            }
            {
#pragma unroll
                for (int i = 0; i < 16; ++i) {
                    int idxq = i * 256 + tid;
                    int row = idxq >> 5, col = idxq & 31;
                    int grw;
                    if (MODE == 0) grw = (row >> 5) * HH + j0 + (row & 31);
                    else           grw = j0 + row;
                    sW[row][col] = W[grw * K + kb + col];
                }
            }
            __syncthreads();
#pragma unroll
            for (int k = 0; k < 32; ++k) {
                float a0 = sA[tg][k];
                float a1 = sA[tg + 8][k];
                float w0 = sW[tj][k];
                float w1 = sW[32 + tj][k];
                float w2 = sW[64 + tj][k];
                float w3 = sW[96 + tj][k];
                acc[0][0] += a0 * w0; acc[0][1] += a0 * w1;
                acc[0][2] += a0 * w2; acc[0][3] += a0 * w3;
                acc[1][0] += a1 * w0; acc[1][1] += a1 * w1;
                acc[1][2] += a1 * w2; acc[1][3] += a1 * w3;
            }
        }
    }

    if (MODE == 0) {
        const int j = j0 + tj;
        const float bi = b1[j] + b2[j];
        const float bf = b1[HH + j] + b2[HH + j];
        const float bg = b1[2 * HH + j] + b2[2 * HH + j];
        const float bo = b1[3 * HH + j] + b2[3 * HH + j];
#pragma unroll
        for (int r = 0; r < 2; ++r) {
            int m = m0 + tg + r * 8;
            float gi = acc[r][0] + bi;
            float gf = acc[r][1] + bf;
            float gg = acc[r][2] + bg;
            float go = acc[r][3] + bo;
            float cp = c_in[m * HH + j];
            float c  = sigm(gf) * cp + sigm(gi) * tanhf(gg);
            float h  = sigm(go) * tanhf(c);
            c_out[m * HH + j] = c;
            h_out[m * HH + j] = h;
        }
    } else {
#pragma unroll
        for (int r = 0; r < 2; ++r) {
            int m = m0 + tg + r * 8;
#pragma unroll
            for (int q = 0; q < 4; ++q) {
                int nn = j0 + q * 32 + tj;
                float v = acc[r][q] + b1[nn];
                h_out[m * HH + nn] = fmaxf(v, 0.f);
            }
        }
    }
}

__global__ __launch_bounds__(64) void fc2_kernel(
    const float* __restrict__ z, const float* __restrict__ W,
    const float* __restrict__ b, float* __restrict__ out)
{
    int m = blockIdx.x;
    int lane = threadIdx.x;
    float zr[8];
#pragma unroll
    for (int u = 0; u < 8; ++u) zr[u] = z[m * 512 + u * 64 + lane];
#pragma unroll
    for (int o = 0; o < 8; ++o) {
        float s = 0.f;
#pragma unroll
        for (int u = 0; u < 8; ++u) s += zr[u] * W[o * 512 + u * 64 + lane];
#pragma unroll
        for (int off = 32; off > 0; off >>= 1) s += __shfl_down(s, off);
        if (lane == 0) out[m * 8 + o] = s + b[o];
    }
}

__global__ __launch_bounds__(256) void zero_f_kernel(float* p, int n)
{
    int i = blockIdx.x * 256 + threadIdx.x;
    if (i < n) p[i] = 0.f;
}

// ---------------- host ----------------

extern "C" void kernel_launch(void* const* d_in, const int* in_sizes, int n_in,
                              void* d_out, int out_size, void* d_ws, size_t ws_size,
                              hipStream_t stream)
{
    const float* x     = (const float*)d_in[0];
    const float* W_ih0 = (const float*)d_in[1];
    const float* W_hh0 = (const float*)d_in[2];
    const float* b_ih0 = (const float*)d_in[3];
    const float* b_hh0 = (const float*)d_in[4];
    const float* W_ih1 = (const float*)d_in[5];
    const float* W_hh1 = (const float*)d_in[6];
    const float* b_ih1 = (const float*)d_in[7];
    const float* b_hh1 = (const float*)d_in[8];
    const float* W_fc1 = (const float*)d_in[9];
    const float* b_fc1 = (const float*)d_in[10];
    const float* W_fc2 = (const float*)d_in[11];
    const float* b_fc2 = (const float*)d_in[12];
    float* out = (float*)d_out;

    const size_t S  = (size_t)BB * HH;        // 131072 elems
    const size_t SB = S * sizeof(u16);        // 262144 B
    const size_t SF = S * sizeof(float);      // 524288 B
    const size_t XN = (size_t)BB * TLEN * DD; // 8388608

    const size_t ZERO = 4 * SB + 1024;        // h0[2], h1[B], barriers
    const size_t NEED = ZERO + 6 * SB /*h0[0..1], h1[A]*/ +
                        2 * SF /*h1last,zfc*/ + 2 * XN * 2 /*x split*/ +
                        2 * 131072 * 2 /*Wih0*/ + 3 * 2 * 1048576 * 2 /*Whh0,Wih1,Whh1*/;

    if (ws_size >= NEED) {
        char* W = (char*)d_ws;
        size_t o = 0;
        u16 *h0hi[3], *h0lo[3], *h1hi[2], *h1lo[2];
        // zero region first: h0 buf2 (t=-1 state), h1 parity-1 (n=1 read), barriers
        h0hi[2] = (u16*)(W + o); o += SB;
        h0lo[2] = (u16*)(W + o); o += SB;
        h1hi[1] = (u16*)(W + o); o += SB;
        h1lo[1] = (u16*)(W + o); o += SB;
        unsigned* bar = (unsigned*)(W + o); o += 1024;   // 4 groups x (bc0,bc1)
        // rest
        h0hi[0] = (u16*)(W + o); o += SB;
        h0lo[0] = (u16*)(W + o); o += SB;
        h0hi[1] = (u16*)(W + o); o += SB;
        h0lo[1] = (u16*)(W + o); o += SB;
        h1hi[0] = (u16*)(W + o); o += SB;
        h1lo[0] = (u16*)(W + o); o += SB;
        float* h1last = (float*)(W + o); o += SF;
        float* zfc    = (float*)(W + o); o += SF;
        u16* xhi = (u16*)(W + o); o += XN * 2;
        u16* xlo = (u16*)(W + o); o += XN * 2;
        u16* wih0h = (u16*)(W + o); o += 131072 * 2;
        u16* wih0l = (u16*)(W + o); o += 131072 * 2;
        u16* whh0h = (u16*)(W + o); o += 1048576 * 2;
        u16* whh0l = (u16*)(W + o); o += 1048576 * 2;
        u16* wih1h = (u16*)(W + o); o += 1048576 * 2;
        u16* wih1l = (u16*)(W + o); o += 1048576 * 2;
        u16* whh1h = (u16*)(W + o); o += 1048576 * 2;
        u16* whh1l = (u16*)(W + o); o += 1048576 * 2;

        // zero-init: (1MB + 1KB)/4 u32
        zero_kernel<<<1025, 256, 0, stream>>>((unsigned*)d_ws, (int)(ZERO / 4));
        // splits
        split_kernel<<<2048, 256, 0, stream>>>(x, xhi, xlo, (int)XN);
        split_kernel<<<512, 256, 0, stream>>>(W_ih0, wih0h, wih0l, 131072);
        split_kernel<<<2048, 256, 0, stream>>>(W_hh0, whh0h, whh0l, 1048576);
        split_kernel<<<2048, 256, 0, stream>>>(W_ih1, wih1h, wih1l, 1048576);
        split_kernel<<<2048, 256, 0, stream>>>(W_hh1, whh1h, whh1l, 1048576);

        lstm_persistent<<<256, 512, 0, stream>>>(
            xhi, xlo,
            wih0h, wih0l, whh0h, whh0l,
            wih1h, wih1l, whh1h, whh1l,
            b_ih0, b_hh0, b_ih1, b_hh1,
            h0hi[0], h0lo[0], h0hi[1], h0lo[1], h0hi[2], h0lo[2],
            h1hi[0], h1lo[0], h1hi[1], h1lo[1],
            h1last, bar);

        dim3 grid_fc1(BB / 16, 512 / 128);
        gemm_step<1><<<grid_fc1, 256, 0, stream>>>(
            h1last, HH, HH, W_fc1, nullptr, 0, nullptr,
            b_fc1, nullptr, nullptr, nullptr, zfc);
        fc2_kernel<<<BB, 64, 0, stream>>>(zfc, W_fc2, b_fc2, out);
        return;
    }

    // -------- fallback: fp32 path (needs ~3.7 MB ws) --------
    float* wsf = (float*)d_ws;
    float* h0a = wsf + 0 * S;
    float* c0  = wsf + 1 * S;
    float* h1a = wsf + 2 * S;
    float* c1  = wsf + 3 * S;
    float* h0b = wsf + 4 * S;
    float* h1b = wsf + 5 * S;
    float* zb  = wsf + 6 * S;
    float* h0buf[2] = {h0a, h0b};
    float* h1buf[2] = {h1a, h1b};

    zero_f_kernel<<<(int)((4 * S + 255) / 256), 256, 0, stream>>>(wsf, (int)(4 * S));

    dim3 grid_lstm(BB / 16, HH / 32);
    for (int t = 0; t < TLEN; ++t) {
        const float* xt = x + (size_t)t * DD;
        gemm_step<0><<<grid_lstm, 256, 0, stream>>>(
            xt, TLEN * DD, DD, W_ih0,
            h0buf[t & 1], HH, W_hh0,
            b_ih0, b_hh0, c0, c0, h0buf[(t + 1) & 1]);
        gemm_step<0><<<grid_lstm, 256, 0, stream>>>(
            h0buf[(t + 1) & 1], HH, HH, W_ih1,
            h1buf[t & 1], HH, W_hh1,
            b_ih1, b_hh1, c1, c1, h1buf[(t + 1) & 1]);
    }
    dim3 grid_fc1(BB / 16, 512 / 128);
    gemm_step<1><<<grid_fc1, 256, 0, stream>>>(
        h1buf[0], HH, HH, W_fc1, nullptr, 0, nullptr,
        b_fc1, nullptr, nullptr, nullptr, zb);
    fc2_kernel<<<BB, 64, 0, stream>>>(zb, W_fc2, b_fc2, out);
}

// Round 9
// 7478.809 us; speedup vs baseline: 2.2851x; 1.1217x over previous
//
#include <hip/hip_runtime.h>
#include <math.h>

typedef unsigned short u16;
typedef __attribute__((ext_vector_type(8))) short short8;
typedef __attribute__((ext_vector_type(4))) float float4v;

#define HH   512
#define BB   256
#define TLEN 512
#define DD   64

__device__ __forceinline__ float sigm(float x) { return 1.0f / (1.0f + __expf(-x)); }

__device__ __forceinline__ u16 bf16rn(float v) {
    unsigned u = __float_as_uint(v);
    u += 0x7fffu + ((u >> 16) & 1u);
    return (u16)(u >> 16);
}
__device__ __forceinline__ float bf16tf(u16 h) { return __uint_as_float(((unsigned)h) << 16); }

// ---------------- precompute kernels ----------------

__global__ __launch_bounds__(256) void split_kernel(const float* __restrict__ src,
                                                    u16* __restrict__ hi, u16* __restrict__ lo, int n)
{
    for (int i = blockIdx.x * 256 + threadIdx.x; i < n; i += gridDim.x * 256) {
        float v = src[i];
        u16 h = bf16rn(v);
        hi[i] = h;
        lo[i] = bf16rn(v - bf16tf(h));
    }
}

__global__ __launch_bounds__(256) void zero_kernel(unsigned* p, int n)
{
    int i = blockIdx.x * 256 + threadIdx.x;
    if (i < n) p[i] = 0u;
}

// ---------------- persistent fused LSTM ----------------
// Round-9 = round-4 VERBATIM (proven 7.32 ms) except the spin-wait.
// Sync history: flat-64 lockstep (r4, 7.32) beats tree (r7, 9.12) and
// decoupled 32-wide (r8, 8.39) -> arrival width/depth is NOT the cost.
// New theory: RELAXED agent-scope polls are served by the poller's own
// XCD L2 (not cross-coherent) -> spin sits on a STALE gen value until the
// every-64-iter acquire safety net fires: avg wake ~32*(128cy sleep+load)
// ~= 3us/step. Fix: poll with SYSTEM-scope relaxed loads (sc0+sc1: bypass
// L1+L2, always fresh, NO invalidation side effects - unlike acquire-
// polling, which nuked L2 in round 1). The gen is written by agent-scope
// atomics executing at the coherent point (proven by r2-r8 correctness),
// so system-scope reads observe it. g0 snapshot also SYSTEM scope so the
// snapshot and the polls share one (fresh) view - a stale agent g0 mixed
// with fresh polls could exit the spin early. Single agent ACQUIRE on
// exit keeps h-data freshness (unchanged from r4).

template<int NKT, int C1, bool ROLE1>
__device__ void lstm_body(
    const u16* __restrict__ X1h, const u16* __restrict__ X1l,
    const u16* __restrict__ B1h, const u16* __restrict__ B1l, const int ldb1,
    const u16* __restrict__ B2h, const u16* __restrict__ B2l,
    const float* __restrict__ pbi, const float* __restrict__ pbh,
    u16* __restrict__ h0hA, u16* __restrict__ h0lA,
    u16* __restrict__ h0hB, u16* __restrict__ h0lB,
    u16* __restrict__ h1hA, u16* __restrict__ h1lA,
    u16* __restrict__ h1hB, u16* __restrict__ h1lB,
    float* __restrict__ h1last,
    unsigned* bcnt, unsigned* bgen,
    const int m0, const int j0, u16* smem)
{
    const int tid  = threadIdx.x;
    const int lane = tid & 63;
    const int wv   = tid >> 6;
    const int g    = wv & 3;
    const int kh   = wv >> 2;
    float* sX = (float*)smem;   // [8][64][18] f32 exchange, aliases staging (sync'd)

    // ---- B slice -> registers, once (kh half of K, gate g, 16 j-cols) ----
    short8 rBh[NKT], rBl[NKT];
    {
        const size_t brow = (size_t)(g * HH + j0 + (lane & 15));
        const int kq = (lane >> 4) * 8;
#pragma unroll
        for (int i = 0; i < NKT; ++i) {
            const int kt = kh * NKT + i;
            const u16 *ph, *pl;
            if (kt < C1) {
                ph = B1h + brow * (size_t)ldb1 + kt * 32 + kq;
                pl = B1l + brow * (size_t)ldb1 + kt * 32 + kq;
            } else {
                ph = B2h + brow * HH + (size_t)(kt - C1) * 32 + kq;
                pl = B2l + brow * HH + (size_t)(kt - C1) * 32 + kq;
            }
            rBh[i] = *(const short8*)ph;
            rBl[i] = *(const short8*)pl;
        }
    }

    // ---- staging constants: 2 x 16B per thread per chunk (16 KB/buffer) ----
    // tile (half,hl): 64 rows x 32k u16; row = 64B; 16B-slot XOR swizzle.
    int r_[2], ks_[2], hl_[2], half_[2], loff_[2];
#pragma unroll
    for (int q = 0; q < 2; ++q) {
        const int idx  = q * 512 + tid;
        const int tile = idx >> 8;          // 0..3 = half*2 + hilo
        half_[q] = tile >> 1;
        hl_[q]   = tile & 1;
        const int t8 = idx & 255;
        const int r  = t8 >> 2;
        const int k3 = t8 & 3;
        r_[q]  = r;
        ks_[q] = k3 * 8;                    // global k sub-offset (unswizzled)
        loff_[q] = tile * 2048 + r * 32 + ((k3 ^ ((r >> 1) & 3)) * 8);
    }

    // ---- A-frag read offsets (swizzled; row = mt*16 + cR, mt*16 keeps swizzle) ----
    const int cR = lane & 15, q4 = lane >> 4;
    const int abase = kh * 4096 + cR * 32 + ((q4 ^ ((cR >> 1) & 3)) * 8);

    // ---- epilogue constants ----
    const int jj  = j0 + (tid & 15);
    const int mb2 = (tid >> 4) * 2;
    const float bI = pbi[jj] + pbh[jj];
    const float bF = pbi[HH + jj] + pbh[HH + jj];
    const float bG = pbi[2 * HH + jj] + pbh[2 * HH + jj];
    const float bO = pbi[3 * HH + jj] + pbh[3 * HH + jj];
    float cst0 = 0.f, cst1 = 0.f;           // c-state in registers

    for (int n = 0; n <= TLEN; ++n) {
        const int rb = n & 1;
        const bool active = ROLE1 ? (n > 0) : (n < TLEN);
        if (active) {
            const u16 *A1h_, *A1l_, *A2h_, *A2l_;
            u16 *wh, *wl;
            size_t ld1;
            if (ROLE1) {
                A1h_ = rb ? h0hB : h0hA; A1l_ = rb ? h0lB : h0lA;
                A2h_ = rb ? h1hB : h1hA; A2l_ = rb ? h1lB : h1lA;
                wh   = rb ? h1hA : h1hB; wl   = rb ? h1lA : h1lB;
                ld1 = HH;
            } else {
                A1h_ = X1h + (size_t)n * DD; A1l_ = X1l + (size_t)n * DD;
                A2h_ = rb ? h0hB : h0hA;     A2l_ = rb ? h0lB : h0lA;
                wh   = rb ? h0hA : h0hB;     wl   = rb ? h0lA : h0lB;
                ld1 = (size_t)TLEN * DD;
            }

            auto srcp = [&](int kt, int r, int ks, int lo) -> const u16* {
                if (kt < C1) return (lo ? A1l_ : A1h_) + (size_t)(m0 + r) * ld1 + kt * 32 + ks;
                return (lo ? A2l_ : A2h_) + (size_t)(m0 + r) * HH + (size_t)(kt - C1) * 32 + ks;
            };

            float4v acc[4];
#pragma unroll
            for (int mt = 0; mt < 4; ++mt) acc[mt] = (float4v){0.f, 0.f, 0.f, 0.f};

            // ---- depth-2 prefetch pipeline; chunk c lives in reg-set c&1 ----
            short8 vS[2][2];
            vS[0][0] = *(const short8*)srcp(half_[0] * NKT + 0, r_[0], ks_[0], hl_[0]);
            vS[0][1] = *(const short8*)srcp(half_[1] * NKT + 0, r_[1], ks_[1], hl_[1]);
            if (NKT > 1) {
                vS[1][0] = *(const short8*)srcp(half_[0] * NKT + 1, r_[0], ks_[0], hl_[0]);
                vS[1][1] = *(const short8*)srcp(half_[1] * NKT + 1, r_[1], ks_[1], hl_[1]);
            }
            *(short8*)&smem[loff_[0]] = vS[0][0];   // stage chunk 0 -> buf0
            *(short8*)&smem[loff_[1]] = vS[0][1];

#pragma unroll
            for (int i = 0; i < NKT; ++i) {
                __syncthreads();               // buf[i&1] staged; prev reads done
                const int buf = i & 1;
                if (i + 1 < NKT) {             // stage chunk i+1 into buf^1
                    *(short8*)&smem[(buf ^ 1) * 8192 + loff_[0]] = vS[(i + 1) & 1][0];
                    *(short8*)&smem[(buf ^ 1) * 8192 + loff_[1]] = vS[(i + 1) & 1][1];
                }
                if (i + 2 < NKT) {             // issue loads for chunk i+2
                    vS[i & 1][0] = *(const short8*)srcp(half_[0] * NKT + i + 2, r_[0], ks_[0], hl_[0]);
                    vS[i & 1][1] = *(const short8*)srcp(half_[1] * NKT + i + 2, r_[1], ks_[1], hl_[1]);
                }
                const int ab = buf * 8192 + abase;
                short8 aH[4], aL[4];
#pragma unroll
                for (int mt = 0; mt < 4; ++mt) {
                    aH[mt] = *(const short8*)&smem[ab + mt * 512];
                    aL[mt] = *(const short8*)&smem[ab + 2048 + mt * 512];
                }
#pragma unroll
                for (int mt = 0; mt < 4; ++mt) {
                    acc[mt] = __builtin_amdgcn_mfma_f32_16x16x32_bf16(aH[mt], rBh[i], acc[mt], 0, 0, 0);
                    acc[mt] = __builtin_amdgcn_mfma_f32_16x16x32_bf16(aH[mt], rBl[i], acc[mt], 0, 0, 0);
                    acc[mt] = __builtin_amdgcn_mfma_f32_16x16x32_bf16(aL[mt], rBh[i], acc[mt], 0, 0, 0);
                }
            }

            // ---- gate/k-half exchange via LDS ----
            __syncthreads();
#pragma unroll
            for (int mt = 0; mt < 4; ++mt)
#pragma unroll
                for (int r = 0; r < 4; ++r)
                    sX[wv * 1152 + (mt * 16 + (lane >> 4) * 4 + r) * 18 + (lane & 15)] = acc[mt][r];
            __syncthreads();

#pragma unroll
            for (int p = 0; p < 2; ++p) {
                const int m = mb2 + p;
                const int xb = m * 18 + (tid & 15);
                const float gi = sX[0 * 1152 + xb] + sX[4 * 1152 + xb] + bI;
                const float gf = sX[1 * 1152 + xb] + sX[5 * 1152 + xb] + bF;
                const float gg = sX[2 * 1152 + xb] + sX[6 * 1152 + xb] + bG;
                const float go = sX[3 * 1152 + xb] + sX[7 * 1152 + xb] + bO;
                const float cp = p ? cst1 : cst0;
                const float cn = sigm(gf) * cp + sigm(gi) * tanhf(gg);
                const float h  = sigm(go) * tanhf(cn);
                if (p) cst1 = cn; else cst0 = cn;
                const size_t off = (size_t)(m0 + m) * HH + jj;
                const u16 hv = bf16rn(h);
                wh[off] = hv;
                wl[off] = bf16rn(h - bf16tf(hv));
                if (ROLE1 && n == TLEN) h1last[off] = h;
            }
        }

        // ---- m-group barrier: r4 flat gen protocol; SYSTEM-scope fresh polls ----
        __syncthreads();   // drains vmcnt(0): h stores are in L2 before release
        if (tid == 0) {
            // g0 snapshot SYSTEM scope: same fresh view as the polls (a stale
            // agent-scope snapshot + fresh polls could exit the spin early).
            const unsigned g0 = __hip_atomic_load(bgen, __ATOMIC_RELAXED, __HIP_MEMORY_SCOPE_SYSTEM);
            const unsigned a = __hip_atomic_fetch_add(bcnt, 1u, __ATOMIC_RELEASE, __HIP_MEMORY_SCOPE_AGENT);
            if (a == 63u) {
                __hip_atomic_store(bcnt, 0u, __ATOMIC_RELAXED, __HIP_MEMORY_SCOPE_AGENT);
                __hip_atomic_store(bgen, g0 + 1u, __ATOMIC_RELEASE, __HIP_MEMORY_SCOPE_AGENT);
            } else {
                // SYSTEM relaxed load: bypasses L1+L2 -> always coherent-point
                // fresh; no invalidation side effects. Wake = ~1 poll period.
                while (__hip_atomic_load(bgen, __ATOMIC_RELAXED, __HIP_MEMORY_SCOPE_SYSTEM) == g0)
                    __builtin_amdgcn_s_sleep(1);
            }
            // single acquire: L1/L2 fresh for next step's h reads (B is in regs,
            // so the invalidate no longer costs a weight refetch).
            (void)__hip_atomic_load(bgen, __ATOMIC_ACQUIRE, __HIP_MEMORY_SCOPE_AGENT);
        }
        __syncthreads();
    }
}

__global__ __launch_bounds__(512, 2) void lstm_persistent(
    const u16* __restrict__ xhi, const u16* __restrict__ xlo,
    const u16* __restrict__ Wih0h, const u16* __restrict__ Wih0l,
    const u16* __restrict__ Whh0h, const u16* __restrict__ Whh0l,
    const u16* __restrict__ Wih1h, const u16* __restrict__ Wih1l,
    const u16* __restrict__ Whh1h, const u16* __restrict__ Whh1l,
    const float* __restrict__ bi0, const float* __restrict__ bh0,
    const float* __restrict__ bi1, const float* __restrict__ bh1,
    u16* h0hA, u16* h0lA, u16* h0hB, u16* h0lB,
    u16* h1hA, u16* h1lA, u16* h1hB, u16* h1lB,
    float* __restrict__ h1last, unsigned* bar)
{
    __shared__ u16 smem[18432];   // 32KB staging (2 bufs) / 36.9KB exchange (aliased)
    const bool role1 = (blockIdx.x >= 128);
    const int idx = blockIdx.x & 127;
    const int m0 = (idx & 3) * 64;
    const int j0 = (idx >> 2) * 16;
    const int gid = idx & 3;
    unsigned* bcnt = bar + gid * 64;
    unsigned* bgen = bar + gid * 64 + 32;

    if (role1)
        lstm_body<16, 16, true>(nullptr, nullptr,
            Wih1h, Wih1l, HH, Whh1h, Whh1l, bi1, bh1,
            h0hA, h0lA, h0hB, h0lB, h1hA, h1lA, h1hB, h1lB,
            h1last, bcnt, bgen, m0, j0, smem);
    else
        lstm_body<9, 2, false>(xhi, xlo,
            Wih0h, Wih0l, DD, Whh0h, Whh0l, bi0, bh0,
            h0hA, h0lA, h0hB, h0lB, h1hA, h1lA, h1hB, h1lB,
            nullptr, bcnt, bgen, m0, j0, smem);
}

// ---------------- FC head (fp32, proven) ----------------

template <int MODE>
__global__ __launch_bounds__(256) void gemm_step(
    const float* __restrict__ A1, int lda1, int K1, const float* __restrict__ W1,
    const float* __restrict__ A2, int K2, const float* __restrict__ W2,
    const float* __restrict__ b1, const float* __restrict__ b2,
    const float* __restrict__ c_in, float* __restrict__ c_out,
    float* __restrict__ h_out)
{
    __shared__ float sA[16][33];
    __shared__ float sW[128][33];

    const int tid = threadIdx.x;
    const int tj  = tid & 31;
    const int tg  = tid >> 5;
    const int m0  = blockIdx.x * 16;
    const int j0  = blockIdx.y * ((MODE == 0) ? 32 : 128);

    float acc[2][4] = {{0.f, 0.f, 0.f, 0.f}, {0.f, 0.f, 0.f, 0.f}};

    for (int seg = 0; seg < 2; ++seg) {
        const float* A  = seg ? A2 : A1;
        const float* W  = seg ? W2 : W1;
        const int    K  = seg ? K2 : K1;
        const int    ld = seg ? HH : lda1;
        if (K == 0) continue;
        for (int kb = 0; kb < K; kb += 32) {
            __syncthreads();
            {
                int idxq = tid;
#pragma unroll
                for (int r = 0; r < 2; ++r, idxq += 256) {
                    int row = idxq >> 5, col = idxq & 31;
                    sA[row][col] = A[(m0 + row) * ld + kb + col];
                }
            }
            {
#pragma unroll
                for (int i = 0; i < 16; ++i) {
                    int idxq = i * 256 + tid;
                    int row = idxq >> 5, col = idxq & 31;
                    int grw;
                    if (MODE == 0) grw = (row >> 5) * HH + j0 + (row & 31);
                    else           grw = j0 + row;
                    sW[row][col] = W[grw * K + kb + col];
                }
            }
            __syncthreads();
#pragma unroll
            for (int k = 0; k < 32; ++k) {
                float a0 = sA[tg][k];
                float a1 = sA[tg + 8][k];
                float w0 = sW[tj][k];
                float w1 = sW[32 + tj][k];
                float w2 = sW[64 + tj][k];
                float w3 = sW[96 + tj][k];
                acc[0][0] += a0 * w0; acc[0][1] += a0 * w1;
                acc[0][2] += a0 * w2; acc[0][3] += a0 * w3;
                acc[1][0] += a1 * w0; acc[1][1] += a1 * w1;
                acc[1][2] += a1 * w2; acc[1][3] += a1 * w3;
            }
        }
    }

    if (MODE == 0) {
        const int j = j0 + tj;
        const float bi = b1[j] + b2[j];
        const float bf = b1[HH + j] + b2[HH + j];
        const float bg = b1[2 * HH + j] + b2[2 * HH + j];
        const float bo = b1[3 * HH + j] + b2[3 * HH + j];
#pragma unroll
        for (int r = 0; r < 2; ++r) {
            int m = m0 + tg + r * 8;
            float gi = acc[r][0] + bi;
            float gf = acc[r][1] + bf;
            float gg = acc[r][2] + bg;
            float go = acc[r][3] + bo;
            float cp = c_in[m * HH + j];
            float c  = sigm(gf) * cp + sigm(gi) * tanhf(gg);
            float h  = sigm(go) * tanhf(c);
            c_out[m * HH + j] = c;
            h_out[m * HH + j] = h;
        }
    } else {
#pragma unroll
        for (int r = 0; r < 2; ++r) {
            int m = m0 + tg + r * 8;
#pragma unroll
            for (int q = 0; q < 4; ++q) {
                int nn = j0 + q * 32 + tj;
                float v = acc[r][q] + b1[nn];
                h_out[m * HH + nn] = fmaxf(v, 0.f);
            }
        }
    }
}

__global__ __launch_bounds__(64) void fc2_kernel(
    const float* __restrict__ z, const float* __restrict__ W,
    const float* __restrict__ b, float* __restrict__ out)
{
    int m = blockIdx.x;
    int lane = threadIdx.x;
    float zr[8];
#pragma unroll
    for (int u = 0; u < 8; ++u) zr[u] = z[m * 512 + u * 64 + lane];
#pragma unroll
    for (int o = 0; o < 8; ++o) {
        float s = 0.f;
#pragma unroll
        for (int u = 0; u < 8; ++u) s += zr[u] * W[o * 512 + u * 64 + lane];
#pragma unroll
        for (int off = 32; off > 0; off >>= 1) s += __shfl_down(s, off);
        if (lane == 0) out[m * 8 + o] = s + b[o];
    }
}

__global__ __launch_bounds__(256) void zero_f_kernel(float* p, int n)
{
    int i = blockIdx.x * 256 + threadIdx.x;
    if (i < n) p[i] = 0.f;
}

// ---------------- host ----------------

extern "C" void kernel_launch(void* const* d_in, const int* in_sizes, int n_in,
                              void* d_out, int out_size, void* d_ws, size_t ws_size,
                              hipStream_t stream)
{
    const float* x     = (const float*)d_in[0];
    const float* W_ih0 = (const float*)d_in[1];
    const float* W_hh0 = (const float*)d_in[2];
    const float* b_ih0 = (const float*)d_in[3];
    const float* b_hh0 = (const float*)d_in[4];
    const float* W_ih1 = (const float*)d_in[5];
    const float* W_hh1 = (const float*)d_in[6];
    const float* b_ih1 = (const float*)d_in[7];
    const float* b_hh1 = (const float*)d_in[8];
    const float* W_fc1 = (const float*)d_in[9];
    const float* b_fc1 = (const float*)d_in[10];
    const float* W_fc2 = (const float*)d_in[11];
    const float* b_fc2 = (const float*)d_in[12];
    float* out = (float*)d_out;

    const size_t S  = (size_t)BB * HH;        // 131072 elems
    const size_t SB = S * sizeof(u16);        // 262144 B
    const size_t SF = S * sizeof(float);      // 524288 B
    const size_t XN = (size_t)BB * TLEN * DD; // 8388608

    const size_t NEED = 2097152 + 1024 /*zero region incl. barriers*/ +
                        4 * SB /*other h bufs*/ +
                        2 * SF /*h1last,zfc*/ + 2 * XN * 2 /*x split*/ +
                        2 * 131072 * 2 /*Wih0*/ + 3 * 2 * 1048576 * 2 /*Whh0,Wih1,Whh1*/;

    if (ws_size >= NEED) {
        char* W = (char*)d_ws;
        size_t o = 0;
        u16 *h0hi[2], *h0lo[2], *h1hi[2], *h1lo[2];
        // zero region first (2 MB + 1 KB): initial-parity h bufs, pad, barriers
        h0hi[0] = (u16*)(W + o); o += SB;
        h0lo[0] = (u16*)(W + o); o += SB;
        h1hi[1] = (u16*)(W + o); o += SB;
        h1lo[1] = (u16*)(W + o); o += SB;
        float* pad0 = (float*)(W + o); o += SF;   // kept for layout stability
        float* pad1 = (float*)(W + o); o += SF;
        unsigned* bar = (unsigned*)(W + o); o += 1024;   // 4 groups x (cnt,gen)
        (void)pad0; (void)pad1;
        // rest
        h0hi[1] = (u16*)(W + o); o += SB;
        h0lo[1] = (u16*)(W + o); o += SB;
        h1hi[0] = (u16*)(W + o); o += SB;
        h1lo[0] = (u16*)(W + o); o += SB;
        float* h1last = (float*)(W + o); o += SF;
        float* zfc    = (float*)(W + o); o += SF;
        u16* xhi = (u16*)(W + o); o += XN * 2;
        u16* xlo = (u16*)(W + o); o += XN * 2;
        u16* wih0h = (u16*)(W + o); o += 131072 * 2;
        u16* wih0l = (u16*)(W + o); o += 131072 * 2;
        u16* whh0h = (u16*)(W + o); o += 1048576 * 2;
        u16* whh0l = (u16*)(W + o); o += 1048576 * 2;
        u16* wih1h = (u16*)(W + o); o += 1048576 * 2;
        u16* wih1l = (u16*)(W + o); o += 1048576 * 2;
        u16* whh1h = (u16*)(W + o); o += 1048576 * 2;
        u16* whh1l = (u16*)(W + o); o += 1048576 * 2;

        // zero-init: 2 MB + 1 KB = 524544 u32
        zero_kernel<<<2049, 256, 0, stream>>>((unsigned*)d_ws, 524544);
        // splits
        split_kernel<<<2048, 256, 0, stream>>>(x, xhi, xlo, (int)XN);
        split_kernel<<<512, 256, 0, stream>>>(W_ih0, wih0h, wih0l, 131072);
        split_kernel<<<2048, 256, 0, stream>>>(W_hh0, whh0h, whh0l, 1048576);
        split_kernel<<<2048, 256, 0, stream>>>(W_ih1, wih1h, wih1l, 1048576);
        split_kernel<<<2048, 256, 0, stream>>>(W_hh1, whh1h, whh1l, 1048576);

        lstm_persistent<<<256, 512, 0, stream>>>(
            xhi, xlo,
            wih0h, wih0l, whh0h, whh0l,
            wih1h, wih1l, whh1h, whh1l,
            b_ih0, b_hh0, b_ih1, b_hh1,
            h0hi[0], h0lo[0], h0hi[1], h0lo[1],
            h1hi[0], h1lo[0], h1hi[1], h1lo[1],
            h1last, bar);

        dim3 grid_fc1(BB / 16, 512 / 128);
        gemm_step<1><<<grid_fc1, 256, 0, stream>>>(
            h1last, HH, HH, W_fc1, nullptr, 0, nullptr,
            b_fc1, nullptr, nullptr, nullptr, zfc);
        fc2_kernel<<<BB, 64, 0, stream>>>(zfc, W_fc2, b_fc2, out);
        return;
    }

    // -------- fallback: fp32 path (needs ~3.7 MB ws) --------
    float* wsf = (float*)d_ws;
    float* h0a = wsf + 0 * S;
    float* c0  = wsf + 1 * S;
    float* h1a = wsf + 2 * S;
    float* c1  = wsf + 3 * S;
    float* h0b = wsf + 4 * S;
    float* h1b = wsf + 5 * S;
    float* zb  = wsf + 6 * S;
    float* h0buf[2] = {h0a, h0b};
    float* h1buf[2] = {h1a, h1b};

    zero_f_kernel<<<(int)((4 * S + 255) / 256), 256, 0, stream>>>(wsf, (int)(4 * S));

    dim3 grid_lstm(BB / 16, HH / 32);
    for (int t = 0; t < TLEN; ++t) {
        const float* xt = x + (size_t)t * DD;
        gemm_step<0><<<grid_lstm, 256, 0, stream>>>(
            xt, TLEN * DD, DD, W_ih0,
            h0buf[t & 1], HH, W_hh0,
            b_ih0, b_hh0, c0, c0, h0buf[(t + 1) & 1]);
        gemm_step<0><<<grid_lstm, 256, 0, stream>>>(
            h0buf[(t + 1) & 1], HH, HH, W_ih1,
            h1buf[t & 1], HH, W_hh1,
            b_ih1, b_hh1, c1, c1, h1buf[(t + 1) & 1]);
    }
    dim3 grid_fc1(BB / 16, 512 / 128);
    gemm_step<1><<<grid_fc1, 256, 0, stream>>>(
        h1buf[0], HH, HH, W_fc1, nullptr, 0, nullptr,
        b_fc1, nullptr, nullptr, nullptr, zb);
    fc2_kernel<<<BB, 64, 0, stream>>>(zb, W_fc2, b_fc2, out);
}